// Round 8
// baseline (413.058 us; speedup 1.0000x reference)
//
#include <hip/hip_runtime.h>
#include <math.h>

// ---------------------------------------------------------------------------
// AFNO3D + LoRA, B=4 H=W=L=64 C=64, modes kh<32 kw<32 kl<8, NB=8 BS=8 R=8.
//
// 4-kernel pipeline (intermediates in d_ws):
//   K1a: DFT-L (real->8 modes)   x -> y1[bh][kl][w][c]
//   K1b: DFT-W (64 -> 32 modes)  y1 -> y2[b][kl][kw][h][c]
//   K2 : DFT-H + block-diag complex MLP (LoRA) + iDFT-H in LDS
//   K3 : stage z2 slab -> iDFT-W (regs) -> iDFT-L + residual
//
// R8 change: radix-2 folding in every DFT loop (e((t+32)k/64)=(-1)^k e(tk/64)):
//   form E=a+b, O=a-b once, accumulate even-k modes from E and odd-k from O.
//   Halves FMA count in k1a/k1b/kc(DFT-H & iDFT-H)/k3(iDFT-L); identical
//   arithmetic values (reassociation only). kc sT shrinks 17->8.7 KB.
// fp32 throughout. Ortho scaling: 1/512 in K2 (pre-MLP) and 1/512 in K3.
// ---------------------------------------------------------------------------

#define PI2_64 0.09817477042468103f   // 2*pi/64

__device__ __forceinline__ float gelu_exact(float t) {
    return 0.5f * t * (1.0f + erff(t * 0.7071067811865475f));
}

// ===========================================================================
// K1a: DFT along L (real -> 8 complex modes), radix-2 folded.
// Block = (bh, w8): 256 threads = 8 w x 32 c-pairs. Grid 2048.
// y1 float4 layout: [bh][kl][w][cp]  (cp = c/2; float4 = (re0,im0,re1,im1))
__global__ void __launch_bounds__(256) k1a_dft_l(const float* __restrict__ x,
                                                 float* __restrict__ y1f) {
    __shared__ float2 twT[8][32];        // 2 KB: twT[kl][l] = e(+kl*l/64), l<32
    int tid = threadIdx.x;
    if (tid < 256) {                     // 8*32 = 256 entries
        int k = tid >> 5, l = tid & 31;
        float s, c;
        sincosf(PI2_64 * (float)((k * l) & 63), &s, &c);
        twT[k][l] = make_float2(c, s);
    }
    __syncthreads();

    int bid = blockIdx.x;                // bh*8 + w8
    int w8 = bid & 7, bh = bid >> 3;
    int cp = tid & 31, wl = tid >> 5;
    int w = w8 * 8 + wl;
    const float* xp = x + (size_t)(bh * 64 + w) * 4096 + 2 * cp;

    float4 A[8];
#pragma unroll
    for (int kl = 0; kl < 8; ++kl) A[kl] = make_float4(0.f, 0.f, 0.f, 0.f);

    for (int l0 = 0; l0 < 32; l0 += 2) {
        float2 v0  = *(const float2*)(xp + (l0 + 0) * 64);
        float2 v0p = *(const float2*)(xp + (l0 + 32) * 64);
        float2 v1  = *(const float2*)(xp + (l0 + 1) * 64);
        float2 v1p = *(const float2*)(xp + (l0 + 33) * 64);
        float2 E0 = make_float2(v0.x + v0p.x, v0.y + v0p.y);
        float2 O0 = make_float2(v0.x - v0p.x, v0.y - v0p.y);
        float2 E1 = make_float2(v1.x + v1p.x, v1.y + v1p.y);
        float2 O1 = make_float2(v1.x - v1p.x, v1.y - v1p.y);
#pragma unroll
        for (int kl = 0; kl < 8; ++kl) {
            float2 t0 = twT[kl][l0];
            float2 t1 = twT[kl][l0 + 1];
            float2 s0 = (kl & 1) ? O0 : E0;    // static parity per kl
            float2 s1 = (kl & 1) ? O1 : E1;
            A[kl].x += s0.x * t0.x;  A[kl].y -= s0.x * t0.y;   // * e^{-i th}
            A[kl].z += s0.y * t0.x;  A[kl].w -= s0.y * t0.y;
            A[kl].x += s1.x * t1.x;  A[kl].y -= s1.x * t1.y;
            A[kl].z += s1.y * t1.x;  A[kl].w -= s1.y * t1.y;
        }
    }
    float4* y1 = (float4*)y1f;
    size_t base = (size_t)bh * 16384 + (size_t)w * 32 + cp;
#pragma unroll
    for (int kl = 0; kl < 8; ++kl)
        y1[base + kl * 2048] = A[kl];
}

// ===========================================================================
// K1b: DFT along W (64 -> 32 modes), radix-2 folded.
// Block = (bh, kl), 256 threads. Grid 2048.
__global__ void __launch_bounds__(256) k1b_dft_w(const float* __restrict__ y1f,
                                                 float* __restrict__ y2f) {
    __shared__ float4 sD[64 * 32];       // 32 KB  [w][cp]
    __shared__ float2 twT[32][32];       // 8 KB  twT[kw][w] = e(+kw*w/64), w<32
    int tid = threadIdx.x;
#pragma unroll
    for (int e = 0; e < 4; ++e) {
        int idx = e * 256 + tid;         // 1024 entries
        int k = idx >> 5, l = idx & 31;
        float s, c;
        sincosf(PI2_64 * (float)((k * l) & 63), &s, &c);
        twT[k][l] = make_float2(c, s);
    }
    int pos = blockIdx.x;                // bh*8 + kl
    int kl = pos & 7, bh = pos >> 3;
    const float4* src = (const float4*)y1f + (size_t)pos * 2048;
#pragma unroll
    for (int r = 0; r < 8; ++r)
        sD[r * 256 + tid] = src[r * 256 + tid];
    __syncthreads();

    int cp = tid & 31, kwg = tid >> 5;   // 8 kw-groups of 4
    float4 acc[4];
#pragma unroll
    for (int i = 0; i < 4; ++i) acc[i] = make_float4(0.f, 0.f, 0.f, 0.f);

    for (int w = 0; w < 32; ++w) {
        float4 d  = sD[w * 32 + cp];
        float4 dp = sD[(w + 32) * 32 + cp];
        float4 E = make_float4(d.x + dp.x, d.y + dp.y, d.z + dp.z, d.w + dp.w);
        float4 O = make_float4(d.x - dp.x, d.y - dp.y, d.z - dp.z, d.w - dp.w);
#pragma unroll
        for (int i = 0; i < 4; ++i) {
            float2 t = twT[kwg * 4 + i][w];
            float4 s = (i & 1) ? O : E;        // kw parity = i parity
            acc[i].x += s.x * t.x + s.y * t.y;  // * e^{-i th}
            acc[i].y += s.y * t.x - s.x * t.y;
            acc[i].z += s.z * t.x + s.w * t.y;
            acc[i].w += s.w * t.x - s.z * t.y;
        }
    }
    int b = bh >> 6, h = bh & 63;
    float4* y2 = (float4*)y2f;
#pragma unroll
    for (int i = 0; i < 4; ++i) {
        int kw = kwg * 4 + i;
        y2[((size_t)((b * 8 + kl) * 32 + kw) * 64 + h) * 32 + cp] = acc[i];
    }
}

// ===========================================================================
// K2: fused DFT-H (64->32, *1/512) + block-diag complex MLP + iDFT-H (32->64).
// One block per (b,kw,kl). Radix-2 folded both transforms.
__global__ void __launch_bounds__(256) kc_h_mlp(
        const float* __restrict__ y2f, float* __restrict__ z2f,
        const float* __restrict__ w1, const float* __restrict__ b1,
        const float* __restrict__ w2, const float* __restrict__ b2,
        const float* __restrict__ la1rA, const float* __restrict__ la1rB,
        const float* __restrict__ la1iA, const float* __restrict__ la1iB,
        const float* __restrict__ la2rA, const float* __restrict__ la2rB,
        const float* __restrict__ la2iA, const float* __restrict__ la2iB) {
    __shared__ float2 sD[64][64];      // staged input -> folded E/O; sM2 overlay
    __shared__ float2 sT[32][34];      // 8.7 KB: T(h*kh)= (cos,-sin), h<32 kh<32
    __shared__ float2 sM[32][66];
    __shared__ float  sW[4][512];
    __shared__ float  sb1[128], sb2[128];
    int tid = threadIdx.x;
    int pos = blockIdx.x;              // (b*32+kw)*8 + kl
    int kl = pos & 7, kw = (pos >> 3) & 31, b = pos >> 8;

#pragma unroll
    for (int r = 0; r < 4; ++r) {
        int idx = r * 256 + tid;       // 1024 = 32 h x 32 kh
        int h = idx >> 5, kh = idx & 31;
        float sn, cs;
        sincosf(PI2_64 * (float)((h * kh) & 63), &sn, &cs);
        sT[h][kh] = make_float2(cs, -sn);
    }
    const float2* src = (const float2*)y2f + (size_t)((b * 8 + kl) * 32 + kw) * 4096;
#pragma unroll
    for (int r = 0; r < 8; ++r) {
        int f = r * 512 + tid * 2;
        *(float4*)(&sD[f >> 6][f & 63]) = *(const float4*)(src + f);
    }
    {   // LoRA-corrected weights
        const float* As[4]   = {la1rA, la1iA, la2rA, la2iA};
        const float* Bs[4]   = {la1rB, la1iB, la2rB, la2iB};
        const float* base[4] = {w1, w1 + 512, w2, w2 + 512};
#pragma unroll
        for (int e = 0; e < 8; ++e) {
            int flat = tid + e * 256;
            int mat = flat >> 9;
            int rem = flat & 511;
            int n = rem >> 6, i = (rem >> 3) & 7, o = rem & 7;
            const float* A  = As[mat] + n * 64 + i * 8;
            const float* Bp = Bs[mat] + n * 64 + o;
            float s = 0.f;
#pragma unroll
            for (int r = 0; r < 8; ++r) s += A[r] * Bp[r * 8];
            sW[mat][(i * 8 + o) * 8 + n] = base[mat][n * 64 + i * 8 + o] + 0.125f * s;
        }
        if (tid < 128) sb1[tid] = b1[tid];
        else           sb2[tid - 128] = b2[tid - 128];
    }
    __syncthreads();

    // ---- fold rows in place: sD[h] = D[h]+D[h+32], sD[h+32] = D[h]-D[h+32] --
    {
        float4* sd4 = (float4*)&sD[0][0];   // 64 rows x 32 f4
#pragma unroll
        for (int r = 0; r < 4; ++r) {
            int idx = r * 256 + tid;        // 1024 = 32 h x 32 cq
            int h = idx >> 5, cq = idx & 31;
            float4 a = sd4[h * 32 + cq];
            float4 c = sd4[(h + 32) * 32 + cq];
            sd4[h * 32 + cq]        = make_float4(a.x + c.x, a.y + c.y, a.z + c.z, a.w + c.w);
            sd4[(h + 32) * 32 + cq] = make_float4(a.x - c.x, a.y - c.y, a.z - c.z, a.w - c.w);
        }
    }
    __syncthreads();

    // ---- M[kh][c] = (1/512) * sum_{h<32} T[h][kh] * (E|O)[h][c], 4kh x 2c --
    {
        int kh0 = (tid >> 5) * 4;          // multiple of 4: parity of kh0+i = i&1
        int c0  = (tid & 31) * 2;
        float mr[4][2], mi[4][2];
#pragma unroll
        for (int i = 0; i < 4; ++i)
#pragma unroll
            for (int j = 0; j < 2; ++j) { mr[i][j] = 0.f; mi[i][j] = 0.f; }
        for (int h = 0; h < 32; ++h) {
            float4 dE = *(const float4*)(&sD[h][c0]);        // E rows
            float4 dO = *(const float4*)(&sD[h + 32][c0]);   // O rows
            float Er[2] = {dE.x, dE.z}, Ei[2] = {dE.y, dE.w};
            float Or[2] = {dO.x, dO.z}, Oi[2] = {dO.y, dO.w};
            const float4* tT = (const float4*)(&sT[h][kh0]);
            float4 u0 = tT[0], u1 = tT[1];
            float Tr[4] = {u0.x, u0.z, u1.x, u1.z};
            float Ti[4] = {u0.y, u0.w, u1.y, u1.w};
#pragma unroll
            for (int i = 0; i < 4; ++i) {
                const float* Dr = (i & 1) ? Or : Er;
                const float* Di = (i & 1) ? Oi : Ei;
#pragma unroll
                for (int j = 0; j < 2; ++j) {
                    mr[i][j] += Tr[i] * Dr[j] - Ti[i] * Di[j];
                    mi[i][j] += Tr[i] * Di[j] + Ti[i] * Dr[j];
                }
            }
        }
        const float sc = 1.0f / 512.0f;
#pragma unroll
        for (int i = 0; i < 4; ++i)
#pragma unroll
            for (int j = 0; j < 2; ++j)
                sM[kh0 + i][c0 + j] = make_float2(mr[i][j] * sc, mi[i][j] * sc);
    }
    __syncthreads();

    // ---- MLP per (kh, n) ----
    float2* sM2 = (float2*)&sD[0][0];   // [32][66]
    {
        int kh = tid >> 3, n = tid & 7;
        float xr[8], xi[8];
#pragma unroll
        for (int i = 0; i < 8; ++i) {
            float2 v = sM[kh][n * 8 + i];
            xr[i] = v.x; xi[i] = v.y;
        }
        float o1r[8], o1i[8];
#pragma unroll
        for (int o = 0; o < 8; ++o) {
            float br = sb1[n * 8 + o], bi = sb1[64 + n * 8 + o];
            float sr = br - bi, si = br + bi;
#pragma unroll
            for (int i = 0; i < 8; ++i) {
                float wr = sW[0][(i * 8 + o) * 8 + n];
                float wi = sW[1][(i * 8 + o) * 8 + n];
                sr += xr[i] * wr - xi[i] * wi;
                si += xi[i] * wr + xr[i] * wi;
            }
            o1r[o] = gelu_exact(sr);
            o1i[o] = gelu_exact(si);
        }
#pragma unroll
        for (int o = 0; o < 8; ++o) {
            float br = sb2[n * 8 + o], bi = sb2[64 + n * 8 + o];
            float sr = br - bi, si = br + bi;
#pragma unroll
            for (int i = 0; i < 8; ++i) {
                float wr = sW[2][(i * 8 + o) * 8 + n];
                float wi = sW[3][(i * 8 + o) * 8 + n];
                sr += o1r[i] * wr - o1i[i] * wi;
                si += o1i[i] * wr + o1r[i] * wi;
            }
            sM2[kh * 66 + n * 8 + o] = make_float2(sr, si);
        }
    }
    __syncthreads();

    // ---- iDFT-H folded: out[h]=SE+SO, out[h+32]=SE-SO (2h x 4c tile) ----
    {
        int h0 = (tid >> 4) * 2;           // h0 in {0,2,...,30}
        int c0 = (tid & 15) * 4;
        float SEr[2][4], SEi[2][4], SOr[2][4], SOi[2][4];
#pragma unroll
        for (int r = 0; r < 2; ++r)
#pragma unroll
            for (int j = 0; j < 4; ++j) {
                SEr[r][j] = 0.f; SEi[r][j] = 0.f;
                SOr[r][j] = 0.f; SOi[r][j] = 0.f;
            }
        for (int khp = 0; khp < 16; ++khp) {
            // even kh = 2*khp -> SE ; odd kh = 2*khp+1 -> SO
#pragma unroll
            for (int par = 0; par < 2; ++par) {
                int kh = 2 * khp + par;
                float2 T0 = sT[h0 + 0][kh];
                float2 T1 = sT[h0 + 1][kh];
                const float4* tM = (const float4*)(sM2 + kh * 66 + c0);
                float4 m0 = tM[0], m1 = tM[1];
                float Mr[4] = {m0.x, m0.z, m1.x, m1.z};
                float Mi[4] = {m0.y, m0.w, m1.y, m1.w};
                float (*Sr)[4] = par ? SOr : SEr;
                float (*Si)[4] = par ? SOi : SEi;
                float Tr[2] = {T0.x, T1.x};
                float Ti[2] = {T0.y, T1.y};
#pragma unroll
                for (int r = 0; r < 2; ++r)
#pragma unroll
                    for (int j = 0; j < 4; ++j) {
                        // conj(T): stored (cos,-sin) -> multiply by (Tr, -Ti)
                        Sr[r][j] += Tr[r] * Mr[j] + Ti[r] * Mi[j];
                        Si[r][j] += Tr[r] * Mi[j] - Ti[r] * Mr[j];
                    }
            }
        }
        float2* dst = (float2*)z2f + (size_t)((b * 8 + kl) * 32 + kw) * 4096;
#pragma unroll
        for (int r = 0; r < 2; ++r) {
            float4* dA = (float4*)(dst + (h0 + r) * 64 + c0);
            dA[0] = make_float4(SEr[r][0] + SOr[r][0], SEi[r][0] + SOi[r][0],
                                SEr[r][1] + SOr[r][1], SEi[r][1] + SOi[r][1]);
            dA[1] = make_float4(SEr[r][2] + SOr[r][2], SEi[r][2] + SOi[r][2],
                                SEr[r][3] + SOr[r][3], SEi[r][3] + SOi[r][3]);
            float4* dB = (float4*)(dst + (h0 + 32 + r) * 64 + c0);
            dB[0] = make_float4(SEr[r][0] - SOr[r][0], SEi[r][0] - SOi[r][0],
                                SEr[r][1] - SOr[r][1], SEi[r][1] - SOi[r][1]);
            dB[1] = make_float4(SEr[r][2] - SOr[r][2], SEi[r][2] - SOi[r][2],
                                SEr[r][3] - SOr[r][3], SEi[r][3] - SOi[r][3]);
        }
    }
}

// ===========================================================================
// K3: fused iDFT-W + iDFT-L + residual.  Block = (b, h, ch); 512 threads.
// iDFT-W even/odd-kw fold (R7); iDFT-L even/odd-kl fold (new): serves l and
// l+32 per iteration.
__global__ void __launch_bounds__(512, 4) k3_wl(const float* __restrict__ x,
                                                const float* __restrict__ z2f,
                                                float* __restrict__ outp) {
    __shared__ float4 sZ[8 * 32 * 16];   // 64 KB, [kl][kw][cp]
    __shared__ float2 twA[8][32];        // 1 KB: twA[k][l] = e(+k*l/64), l<32
    int tid = threadIdx.x;
    int bid = blockIdx.x;
    int b = bid >> 7, h = (bid >> 1) & 63, ch = bid & 1;
    int c0 = ch * 32;

    if (tid < 256) {
        int k = tid >> 5, l = tid & 31;
        float s, c;
        sincosf(PI2_64 * (float)((k * l) & 63), &s, &c);
        twA[k][l] = make_float2(c, s);
    }
    const float4* z2 = (const float4*)z2f;
#pragma unroll
    for (int k = 0; k < 8; ++k) {
        int idx = k * 512 + tid;         // 0..4095 = klkw*16 + cp
        int klkw = idx >> 4, cp = idx & 15;
        sZ[idx] = z2[(size_t)((b * 256 + klkw) * 64 + h) * 32 + ch * 16 + cp];
    }
    __syncthreads();

    int cp = tid & 15, wlo = tid >> 4;   // wlo in [0,32)

    // ---- iDFT-W: even/odd-kw partial sums (shared for rows wlo, wlo+32) ---
    float4 zA[8], zB[8];                 // accumulate E in zA, O in zB
#pragma unroll
    for (int kl = 0; kl < 8; ++kl) {
        zA[kl] = make_float4(0.f, 0.f, 0.f, 0.f);
        zB[kl] = make_float4(0.f, 0.f, 0.f, 0.f);
    }
    float2 u = make_float2(1.f, 0.f);
    float2 su;
    {
        float s, c;
        sincosf(PI2_64 * (float)wlo, &s, &c);
        su = make_float2(c, s);          // e^{+2pi i wlo/64}
    }
    for (int kw = 0; kw < 32; kw += 2) {
#pragma unroll
        for (int kl = 0; kl < 8; ++kl) {
            float4 d = sZ[(kl * 32 + kw) * 16 + cp];
            zA[kl].x += d.x * u.x - d.y * u.y;
            zA[kl].y += d.y * u.x + d.x * u.y;
            zA[kl].z += d.z * u.x - d.w * u.y;
            zA[kl].w += d.w * u.x + d.z * u.y;
        }
        {
            float nr = u.x * su.x - u.y * su.y;
            float ni = u.y * su.x + u.x * su.y;
            u = make_float2(nr, ni);
        }
#pragma unroll
        for (int kl = 0; kl < 8; ++kl) {
            float4 d = sZ[(kl * 32 + kw + 1) * 16 + cp];
            zB[kl].x += d.x * u.x - d.y * u.y;
            zB[kl].y += d.y * u.x + d.x * u.y;
            zB[kl].z += d.z * u.x - d.w * u.y;
            zB[kl].w += d.w * u.x + d.z * u.y;
        }
        {
            float nr = u.x * su.x - u.y * su.y;
            float ni = u.y * su.x + u.x * su.y;
            u = make_float2(nr, ni);
        }
    }
    // zA (row w=wlo) = E+O ; zB (row w=wlo+32) = E-O.
#pragma unroll
    for (int kl = 0; kl < 8; ++kl) {
        float4 e = zA[kl], o = zB[kl];
        zA[kl] = make_float4(e.x + o.x, e.y + o.y, e.z + o.z, e.w + o.w);
        zB[kl] = make_float4(e.x - o.x, e.y - o.y, e.z - o.z, e.w - o.w);
    }

    // ---- iDFT-L folded + residual (numpy irfft: Im(kl=0) dropped) ----
    float zAr0 = zA[0].x, zAr1 = zA[0].z;
    float zBr0 = zB[0].x, zBr1 = zB[0].z;
#pragma unroll
    for (int kl = 1; kl < 8; ++kl) {     // pre-double modes 1..7
        zA[kl].x *= 2.f; zA[kl].y *= 2.f; zA[kl].z *= 2.f; zA[kl].w *= 2.f;
        zB[kl].x *= 2.f; zB[kl].y *= 2.f; zB[kl].z *= 2.f; zB[kl].w *= 2.f;
    }
    const size_t rowA = (size_t)((b * 64 + h) * 64 + wlo) * 4096;
    const size_t rowB = rowA + (size_t)32 * 4096;
    const float* xpA = x + rowA + c0 + 2 * cp;
    const float* xpB = x + rowB + c0 + 2 * cp;
    float* opA = outp + rowA + c0 + 2 * cp;
    float* opB = outp + rowB + c0 + 2 * cp;
    const float sc = 1.0f / 512.0f;

    for (int l = 0; l < 32; ++l) {
        // loads for l and l+32, both rows (4 float2)
        float2 a0 = *(const float2*)(xpA + l * 64);
        float2 a1 = *(const float2*)(xpA + (l + 32) * 64);
        float2 b0 = *(const float2*)(xpB + l * 64);
        float2 b1 = *(const float2*)(xpB + (l + 32) * 64);
        // even-kl partial (kl = 2,4,6) and odd-kl partial (kl = 1,3,5,7)
        float eA0 = 0.f, eA1 = 0.f, oA0 = 0.f, oA1 = 0.f;
        float eB0 = 0.f, eB1 = 0.f, oB0 = 0.f, oB1 = 0.f;
#pragma unroll
        for (int kl = 2; kl < 8; kl += 2) {
            float2 t = twA[kl][l];
            eA0 += zA[kl].x * t.x - zA[kl].y * t.y;
            eA1 += zA[kl].z * t.x - zA[kl].w * t.y;
            eB0 += zB[kl].x * t.x - zB[kl].y * t.y;
            eB1 += zB[kl].z * t.x - zB[kl].w * t.y;
        }
#pragma unroll
        for (int kl = 1; kl < 8; kl += 2) {
            float2 t = twA[kl][l];
            oA0 += zA[kl].x * t.x - zA[kl].y * t.y;
            oA1 += zA[kl].z * t.x - zA[kl].w * t.y;
            oB0 += zB[kl].x * t.x - zB[kl].y * t.y;
            oB1 += zB[kl].z * t.x - zB[kl].w * t.y;
        }
        float baseA0 = zAr0 + eA0, baseA1 = zAr1 + eA1;
        float baseB0 = zBr0 + eB0, baseB1 = zBr1 + eB1;
        *(float2*)(opA + l * 64) =
            make_float2((baseA0 + oA0) * sc + a0.x, (baseA1 + oA1) * sc + a0.y);
        *(float2*)(opA + (l + 32) * 64) =
            make_float2((baseA0 - oA0) * sc + a1.x, (baseA1 - oA1) * sc + a1.y);
        *(float2*)(opB + l * 64) =
            make_float2((baseB0 + oB0) * sc + b0.x, (baseB1 + oB1) * sc + b0.y);
        *(float2*)(opB + (l + 32) * 64) =
            make_float2((baseB0 - oB0) * sc + b1.x, (baseB1 - oB1) * sc + b1.y);
    }
}

// ===========================================================================
extern "C" void kernel_launch(void* const* d_in, const int* in_sizes, int n_in,
                              void* d_out, int out_size, void* d_ws, size_t ws_size,
                              hipStream_t stream) {
    const float* x     = (const float*)d_in[0];
    const float* w1    = (const float*)d_in[1];
    const float* b1    = (const float*)d_in[2];
    const float* w2    = (const float*)d_in[3];
    const float* b2    = (const float*)d_in[4];
    const float* la1rA = (const float*)d_in[5];
    const float* la1rB = (const float*)d_in[6];
    const float* la1iA = (const float*)d_in[7];
    const float* la1iB = (const float*)d_in[8];
    const float* la2rA = (const float*)d_in[9];
    const float* la2rB = (const float*)d_in[10];
    const float* la2iA = (const float*)d_in[11];
    const float* la2iB = (const float*)d_in[12];
    float* out = (float*)d_out;

    float* ws = (float*)d_ws;
    float* y1 = ws;                    // [256 bh][8 kl][64 w][32 cp] f4 = 67 MB
    float* y2 = ws + 16777216;         // [4][8][32][64][64] complex = 33 MB
    float* z2 = ws + 25165824;         // same as y2

    hipLaunchKernelGGL(k1a_dft_l, dim3(2048), dim3(256), 0, stream, x, y1);
    hipLaunchKernelGGL(k1b_dft_w, dim3(2048), dim3(256), 0, stream, y1, y2);
    hipLaunchKernelGGL(kc_h_mlp,  dim3(1024), dim3(256), 0, stream, y2, z2,
                       w1, b1, w2, b2, la1rA, la1rB, la1iA, la1iB,
                       la2rA, la2rB, la2iA, la2iB);
    hipLaunchKernelGGL(k3_wl,     dim3(512),  dim3(512), 0, stream, x, z2, out);
}

// Round 9
// 362.293 us; speedup vs baseline: 1.1401x; 1.1401x over previous
//
#include <hip/hip_runtime.h>
#include <math.h>

// ---------------------------------------------------------------------------
// AFNO3D + LoRA, B=4 H=W=L=64 C=64, modes kh<32 kw<32 kl<8, NB=8 BS=8 R=8.
//
// 4-kernel pipeline (intermediates in d_ws):
//   K1a: DFT-L (real->8 modes)   x -> y1[bh][kl][w][c]      (radix-2 folded)
//   K1b: DFT-W (64 -> 32 modes)  y1 -> y2[b][kl][kw][h][c]  (radix-2 folded)
//   K2 : DFT-H + MLP(LoRA) + iDFT-H in LDS                  (radix-2 folded)
//   K3 : stage z2 quarter-slab -> iDFT-W (E/O fold) -> iDFT-L (l/l+32 fold)
//        + residual
//
// R9 change: K3 reshaped 512-thr -> 256-thr (quarter-channel slabs).
//   Toolchain empirically pins >=512-thread kernels at 64 VGPR (R4/R5/R8 all
//   spilled: FETCH/WRITE inflated ~200/50 MB, VALUBusy<15%). 256-thr kernels
//   never spill. Same validated folding math, block = (b,h,cq), sZ 32 KB.
// fp32 throughout. Ortho scaling: 1/512 in K2 (pre-MLP) and 1/512 in K3.
// ---------------------------------------------------------------------------

#define PI2_64 0.09817477042468103f   // 2*pi/64

__device__ __forceinline__ float gelu_exact(float t) {
    return 0.5f * t * (1.0f + erff(t * 0.7071067811865475f));
}

// ===========================================================================
// K1a: DFT along L (real -> 8 complex modes), radix-2 folded.
// Block = (bh, w8): 256 threads = 8 w x 32 c-pairs. Grid 2048.
// y1 float4 layout: [bh][kl][w][cp]  (cp = c/2; float4 = (re0,im0,re1,im1))
__global__ void __launch_bounds__(256) k1a_dft_l(const float* __restrict__ x,
                                                 float* __restrict__ y1f) {
    __shared__ float2 twT[8][32];        // 2 KB: twT[kl][l] = e(+kl*l/64), l<32
    int tid = threadIdx.x;
    if (tid < 256) {                     // 8*32 = 256 entries
        int k = tid >> 5, l = tid & 31;
        float s, c;
        sincosf(PI2_64 * (float)((k * l) & 63), &s, &c);
        twT[k][l] = make_float2(c, s);
    }
    __syncthreads();

    int bid = blockIdx.x;                // bh*8 + w8
    int w8 = bid & 7, bh = bid >> 3;
    int cp = tid & 31, wl = tid >> 5;
    int w = w8 * 8 + wl;
    const float* xp = x + (size_t)(bh * 64 + w) * 4096 + 2 * cp;

    float4 A[8];
#pragma unroll
    for (int kl = 0; kl < 8; ++kl) A[kl] = make_float4(0.f, 0.f, 0.f, 0.f);

    for (int l0 = 0; l0 < 32; l0 += 2) {
        float2 v0  = *(const float2*)(xp + (l0 + 0) * 64);
        float2 v0p = *(const float2*)(xp + (l0 + 32) * 64);
        float2 v1  = *(const float2*)(xp + (l0 + 1) * 64);
        float2 v1p = *(const float2*)(xp + (l0 + 33) * 64);
        float2 E0 = make_float2(v0.x + v0p.x, v0.y + v0p.y);
        float2 O0 = make_float2(v0.x - v0p.x, v0.y - v0p.y);
        float2 E1 = make_float2(v1.x + v1p.x, v1.y + v1p.y);
        float2 O1 = make_float2(v1.x - v1p.x, v1.y - v1p.y);
#pragma unroll
        for (int kl = 0; kl < 8; ++kl) {
            float2 t0 = twT[kl][l0];
            float2 t1 = twT[kl][l0 + 1];
            float2 s0 = (kl & 1) ? O0 : E0;    // static parity per kl
            float2 s1 = (kl & 1) ? O1 : E1;
            A[kl].x += s0.x * t0.x;  A[kl].y -= s0.x * t0.y;   // * e^{-i th}
            A[kl].z += s0.y * t0.x;  A[kl].w -= s0.y * t0.y;
            A[kl].x += s1.x * t1.x;  A[kl].y -= s1.x * t1.y;
            A[kl].z += s1.y * t1.x;  A[kl].w -= s1.y * t1.y;
        }
    }
    float4* y1 = (float4*)y1f;
    size_t base = (size_t)bh * 16384 + (size_t)w * 32 + cp;
#pragma unroll
    for (int kl = 0; kl < 8; ++kl)
        y1[base + kl * 2048] = A[kl];
}

// ===========================================================================
// K1b: DFT along W (64 -> 32 modes), radix-2 folded.
// Block = (bh, kl), 256 threads. Grid 2048.
__global__ void __launch_bounds__(256) k1b_dft_w(const float* __restrict__ y1f,
                                                 float* __restrict__ y2f) {
    __shared__ float4 sD[64 * 32];       // 32 KB  [w][cp]
    __shared__ float2 twT[32][32];       // 8 KB  twT[kw][w] = e(+kw*w/64), w<32
    int tid = threadIdx.x;
#pragma unroll
    for (int e = 0; e < 4; ++e) {
        int idx = e * 256 + tid;         // 1024 entries
        int k = idx >> 5, l = idx & 31;
        float s, c;
        sincosf(PI2_64 * (float)((k * l) & 63), &s, &c);
        twT[k][l] = make_float2(c, s);
    }
    int pos = blockIdx.x;                // bh*8 + kl
    int kl = pos & 7, bh = pos >> 3;
    const float4* src = (const float4*)y1f + (size_t)pos * 2048;
#pragma unroll
    for (int r = 0; r < 8; ++r)
        sD[r * 256 + tid] = src[r * 256 + tid];
    __syncthreads();

    int cp = tid & 31, kwg = tid >> 5;   // 8 kw-groups of 4
    float4 acc[4];
#pragma unroll
    for (int i = 0; i < 4; ++i) acc[i] = make_float4(0.f, 0.f, 0.f, 0.f);

    for (int w = 0; w < 32; ++w) {
        float4 d  = sD[w * 32 + cp];
        float4 dp = sD[(w + 32) * 32 + cp];
        float4 E = make_float4(d.x + dp.x, d.y + dp.y, d.z + dp.z, d.w + dp.w);
        float4 O = make_float4(d.x - dp.x, d.y - dp.y, d.z - dp.z, d.w - dp.w);
#pragma unroll
        for (int i = 0; i < 4; ++i) {
            float2 t = twT[kwg * 4 + i][w];
            float4 s = (i & 1) ? O : E;        // kw parity = i parity
            acc[i].x += s.x * t.x + s.y * t.y;  // * e^{-i th}
            acc[i].y += s.y * t.x - s.x * t.y;
            acc[i].z += s.z * t.x + s.w * t.y;
            acc[i].w += s.w * t.x - s.z * t.y;
        }
    }
    int b = bh >> 6, h = bh & 63;
    float4* y2 = (float4*)y2f;
#pragma unroll
    for (int i = 0; i < 4; ++i) {
        int kw = kwg * 4 + i;
        y2[((size_t)((b * 8 + kl) * 32 + kw) * 64 + h) * 32 + cp] = acc[i];
    }
}

// ===========================================================================
// K2: fused DFT-H (64->32, *1/512) + block-diag complex MLP + iDFT-H (32->64).
// One block per (b,kw,kl). Radix-2 folded both transforms. Validated R8.
__global__ void __launch_bounds__(256) kc_h_mlp(
        const float* __restrict__ y2f, float* __restrict__ z2f,
        const float* __restrict__ w1, const float* __restrict__ b1,
        const float* __restrict__ w2, const float* __restrict__ b2,
        const float* __restrict__ la1rA, const float* __restrict__ la1rB,
        const float* __restrict__ la1iA, const float* __restrict__ la1iB,
        const float* __restrict__ la2rA, const float* __restrict__ la2rB,
        const float* __restrict__ la2iA, const float* __restrict__ la2iB) {
    __shared__ float2 sD[64][64];      // staged input -> folded E/O; sM2 overlay
    __shared__ float2 sT[32][34];      // 8.7 KB: T(h*kh)= (cos,-sin), h<32 kh<32
    __shared__ float2 sM[32][66];
    __shared__ float  sW[4][512];
    __shared__ float  sb1[128], sb2[128];
    int tid = threadIdx.x;
    int pos = blockIdx.x;              // (b*32+kw)*8 + kl
    int kl = pos & 7, kw = (pos >> 3) & 31, b = pos >> 8;

#pragma unroll
    for (int r = 0; r < 4; ++r) {
        int idx = r * 256 + tid;       // 1024 = 32 h x 32 kh
        int h = idx >> 5, kh = idx & 31;
        float sn, cs;
        sincosf(PI2_64 * (float)((h * kh) & 63), &sn, &cs);
        sT[h][kh] = make_float2(cs, -sn);
    }
    const float2* src = (const float2*)y2f + (size_t)((b * 8 + kl) * 32 + kw) * 4096;
#pragma unroll
    for (int r = 0; r < 8; ++r) {
        int f = r * 512 + tid * 2;
        *(float4*)(&sD[f >> 6][f & 63]) = *(const float4*)(src + f);
    }
    {   // LoRA-corrected weights
        const float* As[4]   = {la1rA, la1iA, la2rA, la2iA};
        const float* Bs[4]   = {la1rB, la1iB, la2rB, la2iB};
        const float* base[4] = {w1, w1 + 512, w2, w2 + 512};
#pragma unroll
        for (int e = 0; e < 8; ++e) {
            int flat = tid + e * 256;
            int mat = flat >> 9;
            int rem = flat & 511;
            int n = rem >> 6, i = (rem >> 3) & 7, o = rem & 7;
            const float* A  = As[mat] + n * 64 + i * 8;
            const float* Bp = Bs[mat] + n * 64 + o;
            float s = 0.f;
#pragma unroll
            for (int r = 0; r < 8; ++r) s += A[r] * Bp[r * 8];
            sW[mat][(i * 8 + o) * 8 + n] = base[mat][n * 64 + i * 8 + o] + 0.125f * s;
        }
        if (tid < 128) sb1[tid] = b1[tid];
        else           sb2[tid - 128] = b2[tid - 128];
    }
    __syncthreads();

    // ---- fold rows in place: sD[h] = D[h]+D[h+32], sD[h+32] = D[h]-D[h+32] --
    {
        float4* sd4 = (float4*)&sD[0][0];   // 64 rows x 32 f4
#pragma unroll
        for (int r = 0; r < 4; ++r) {
            int idx = r * 256 + tid;        // 1024 = 32 h x 32 cq
            int h = idx >> 5, cq = idx & 31;
            float4 a = sd4[h * 32 + cq];
            float4 c = sd4[(h + 32) * 32 + cq];
            sd4[h * 32 + cq]        = make_float4(a.x + c.x, a.y + c.y, a.z + c.z, a.w + c.w);
            sd4[(h + 32) * 32 + cq] = make_float4(a.x - c.x, a.y - c.y, a.z - c.z, a.w - c.w);
        }
    }
    __syncthreads();

    // ---- M[kh][c] = (1/512) * sum_{h<32} T[h][kh] * (E|O)[h][c], 4kh x 2c --
    {
        int kh0 = (tid >> 5) * 4;          // multiple of 4: parity of kh0+i = i&1
        int c0  = (tid & 31) * 2;
        float mr[4][2], mi[4][2];
#pragma unroll
        for (int i = 0; i < 4; ++i)
#pragma unroll
            for (int j = 0; j < 2; ++j) { mr[i][j] = 0.f; mi[i][j] = 0.f; }
        for (int h = 0; h < 32; ++h) {
            float4 dE = *(const float4*)(&sD[h][c0]);        // E rows
            float4 dO = *(const float4*)(&sD[h + 32][c0]);   // O rows
            float Er[2] = {dE.x, dE.z}, Ei[2] = {dE.y, dE.w};
            float Or[2] = {dO.x, dO.z}, Oi[2] = {dO.y, dO.w};
            const float4* tT = (const float4*)(&sT[h][kh0]);
            float4 u0 = tT[0], u1 = tT[1];
            float Tr[4] = {u0.x, u0.z, u1.x, u1.z};
            float Ti[4] = {u0.y, u0.w, u1.y, u1.w};
#pragma unroll
            for (int i = 0; i < 4; ++i) {
                const float* Dr = (i & 1) ? Or : Er;
                const float* Di = (i & 1) ? Oi : Ei;
#pragma unroll
                for (int j = 0; j < 2; ++j) {
                    mr[i][j] += Tr[i] * Dr[j] - Ti[i] * Di[j];
                    mi[i][j] += Tr[i] * Di[j] + Ti[i] * Dr[j];
                }
            }
        }
        const float sc = 1.0f / 512.0f;
#pragma unroll
        for (int i = 0; i < 4; ++i)
#pragma unroll
            for (int j = 0; j < 2; ++j)
                sM[kh0 + i][c0 + j] = make_float2(mr[i][j] * sc, mi[i][j] * sc);
    }
    __syncthreads();

    // ---- MLP per (kh, n) ----
    float2* sM2 = (float2*)&sD[0][0];   // [32][66]
    {
        int kh = tid >> 3, n = tid & 7;
        float xr[8], xi[8];
#pragma unroll
        for (int i = 0; i < 8; ++i) {
            float2 v = sM[kh][n * 8 + i];
            xr[i] = v.x; xi[i] = v.y;
        }
        float o1r[8], o1i[8];
#pragma unroll
        for (int o = 0; o < 8; ++o) {
            float br = sb1[n * 8 + o], bi = sb1[64 + n * 8 + o];
            float sr = br - bi, si = br + bi;
#pragma unroll
            for (int i = 0; i < 8; ++i) {
                float wr = sW[0][(i * 8 + o) * 8 + n];
                float wi = sW[1][(i * 8 + o) * 8 + n];
                sr += xr[i] * wr - xi[i] * wi;
                si += xi[i] * wr + xr[i] * wi;
            }
            o1r[o] = gelu_exact(sr);
            o1i[o] = gelu_exact(si);
        }
#pragma unroll
        for (int o = 0; o < 8; ++o) {
            float br = sb2[n * 8 + o], bi = sb2[64 + n * 8 + o];
            float sr = br - bi, si = br + bi;
#pragma unroll
            for (int i = 0; i < 8; ++i) {
                float wr = sW[2][(i * 8 + o) * 8 + n];
                float wi = sW[3][(i * 8 + o) * 8 + n];
                sr += o1r[i] * wr - o1i[i] * wi;
                si += o1i[i] * wr + o1r[i] * wi;
            }
            sM2[kh * 66 + n * 8 + o] = make_float2(sr, si);
        }
    }
    __syncthreads();

    // ---- iDFT-H folded: out[h]=SE+SO, out[h+32]=SE-SO (2h x 4c tile) ----
    {
        int h0 = (tid >> 4) * 2;           // h0 in {0,2,...,30}
        int c0 = (tid & 15) * 4;
        float SEr[2][4], SEi[2][4], SOr[2][4], SOi[2][4];
#pragma unroll
        for (int r = 0; r < 2; ++r)
#pragma unroll
            for (int j = 0; j < 4; ++j) {
                SEr[r][j] = 0.f; SEi[r][j] = 0.f;
                SOr[r][j] = 0.f; SOi[r][j] = 0.f;
            }
        for (int khp = 0; khp < 16; ++khp) {
#pragma unroll
            for (int par = 0; par < 2; ++par) {
                int kh = 2 * khp + par;
                float2 T0 = sT[h0 + 0][kh];
                float2 T1 = sT[h0 + 1][kh];
                const float4* tM = (const float4*)(sM2 + kh * 66 + c0);
                float4 m0 = tM[0], m1 = tM[1];
                float Mr[4] = {m0.x, m0.z, m1.x, m1.z};
                float Mi[4] = {m0.y, m0.w, m1.y, m1.w};
                float (*Sr)[4] = par ? SOr : SEr;
                float (*Si)[4] = par ? SOi : SEi;
                float Tr[2] = {T0.x, T1.x};
                float Ti[2] = {T0.y, T1.y};
#pragma unroll
                for (int r = 0; r < 2; ++r)
#pragma unroll
                    for (int j = 0; j < 4; ++j) {
                        // conj(T): stored (cos,-sin) -> multiply by (Tr, -Ti)
                        Sr[r][j] += Tr[r] * Mr[j] + Ti[r] * Mi[j];
                        Si[r][j] += Tr[r] * Mi[j] - Ti[r] * Mr[j];
                    }
            }
        }
        float2* dst = (float2*)z2f + (size_t)((b * 8 + kl) * 32 + kw) * 4096;
#pragma unroll
        for (int r = 0; r < 2; ++r) {
            float4* dA = (float4*)(dst + (h0 + r) * 64 + c0);
            dA[0] = make_float4(SEr[r][0] + SOr[r][0], SEi[r][0] + SOi[r][0],
                                SEr[r][1] + SOr[r][1], SEi[r][1] + SOi[r][1]);
            dA[1] = make_float4(SEr[r][2] + SOr[r][2], SEi[r][2] + SOi[r][2],
                                SEr[r][3] + SOr[r][3], SEi[r][3] + SOi[r][3]);
            float4* dB = (float4*)(dst + (h0 + 32 + r) * 64 + c0);
            dB[0] = make_float4(SEr[r][0] - SOr[r][0], SEi[r][0] - SOi[r][0],
                                SEr[r][1] - SOr[r][1], SEi[r][1] - SOi[r][1]);
            dB[1] = make_float4(SEr[r][2] - SOr[r][2], SEi[r][2] - SOi[r][2],
                                SEr[r][3] - SOr[r][3], SEi[r][3] - SOi[r][3]);
        }
    }
}

// ===========================================================================
// K3: fused iDFT-W + iDFT-L + residual.  Block = (b, h, cq); 256 threads.
// cq = channel quarter (16 channels = 8 float4 lanes). Thread (cpq = tid&7,
// wlo = tid>>3 in [0,32)) handles rows w=wlo and wlo+32 via even/odd-kw fold,
// and l / l+32 via even/odd-kl fold. Grid 1024.
__global__ void __launch_bounds__(256, 2) k3_wl(const float* __restrict__ x,
                                                const float* __restrict__ z2f,
                                                float* __restrict__ outp) {
    __shared__ float4 sZ[8 * 32 * 8];    // 32 KB, [kl][kw][cpq]
    __shared__ float2 twA[8][32];        // 1 KB: twA[k][l] = e(+k*l/64), l<32
    int tid = threadIdx.x;
    int bid = blockIdx.x;                // ((b*64+h)*4 + cq)
    int cq = bid & 3, h = (bid >> 2) & 63, b = bid >> 8;

    {
        int k = tid >> 5, l = tid & 31;  // 256 entries
        float s, c;
        sincosf(PI2_64 * (float)((k * l) & 63), &s, &c);
        twA[k][l] = make_float2(c, s);
    }
    const float4* z2 = (const float4*)z2f;
#pragma unroll
    for (int k = 0; k < 8; ++k) {
        int idx = k * 256 + tid;         // 0..2047 = klkw*8 + cpq
        int klkw = idx >> 3, cpq = idx & 7;
        sZ[idx] = z2[(size_t)((b * 256 + klkw) * 64 + h) * 32 + cq * 8 + cpq];
    }
    __syncthreads();

    int cpq = tid & 7, wlo = tid >> 3;   // wlo in [0,32)

    // ---- iDFT-W: even/odd-kw partial sums (rows wlo, wlo+32) ----
    float4 zA[8], zB[8];                 // E in zA, O in zB
#pragma unroll
    for (int kl = 0; kl < 8; ++kl) {
        zA[kl] = make_float4(0.f, 0.f, 0.f, 0.f);
        zB[kl] = make_float4(0.f, 0.f, 0.f, 0.f);
    }
    float2 u = make_float2(1.f, 0.f);
    float2 su;
    {
        float s, c;
        sincosf(PI2_64 * (float)wlo, &s, &c);
        su = make_float2(c, s);          // e^{+2pi i wlo/64}
    }
    for (int kw = 0; kw < 32; kw += 2) {
#pragma unroll
        for (int kl = 0; kl < 8; ++kl) {
            float4 d = sZ[(kl * 32 + kw) * 8 + cpq];
            zA[kl].x += d.x * u.x - d.y * u.y;
            zA[kl].y += d.y * u.x + d.x * u.y;
            zA[kl].z += d.z * u.x - d.w * u.y;
            zA[kl].w += d.w * u.x + d.z * u.y;
        }
        {
            float nr = u.x * su.x - u.y * su.y;
            float ni = u.y * su.x + u.x * su.y;
            u = make_float2(nr, ni);
        }
#pragma unroll
        for (int kl = 0; kl < 8; ++kl) {
            float4 d = sZ[(kl * 32 + kw + 1) * 8 + cpq];
            zB[kl].x += d.x * u.x - d.y * u.y;
            zB[kl].y += d.y * u.x + d.x * u.y;
            zB[kl].z += d.z * u.x - d.w * u.y;
            zB[kl].w += d.w * u.x + d.z * u.y;
        }
        {
            float nr = u.x * su.x - u.y * su.y;
            float ni = u.y * su.x + u.x * su.y;
            u = make_float2(nr, ni);
        }
    }
    // zA (row w=wlo) = E+O ; zB (row w=wlo+32) = E-O.
#pragma unroll
    for (int kl = 0; kl < 8; ++kl) {
        float4 e = zA[kl], o = zB[kl];
        zA[kl] = make_float4(e.x + o.x, e.y + o.y, e.z + o.z, e.w + o.w);
        zB[kl] = make_float4(e.x - o.x, e.y - o.y, e.z - o.z, e.w - o.w);
    }

    // ---- iDFT-L folded + residual (numpy irfft: Im(kl=0) dropped) ----
    float zAr0 = zA[0].x, zAr1 = zA[0].z;
    float zBr0 = zB[0].x, zBr1 = zB[0].z;
#pragma unroll
    for (int kl = 1; kl < 8; ++kl) {     // pre-double modes 1..7
        zA[kl].x *= 2.f; zA[kl].y *= 2.f; zA[kl].z *= 2.f; zA[kl].w *= 2.f;
        zB[kl].x *= 2.f; zB[kl].y *= 2.f; zB[kl].z *= 2.f; zB[kl].w *= 2.f;
    }
    const size_t rowA = (size_t)((b * 64 + h) * 64 + wlo) * 4096;
    const size_t rowB = rowA + (size_t)32 * 4096;
    const int coff = cq * 16 + 2 * cpq;
    const float* xpA = x + rowA + coff;
    const float* xpB = x + rowB + coff;
    float* opA = outp + rowA + coff;
    float* opB = outp + rowB + coff;
    const float sc = 1.0f / 512.0f;

    for (int l = 0; l < 32; ++l) {
        float2 a0 = *(const float2*)(xpA + l * 64);
        float2 a1 = *(const float2*)(xpA + (l + 32) * 64);
        float2 b0 = *(const float2*)(xpB + l * 64);
        float2 b1 = *(const float2*)(xpB + (l + 32) * 64);
        float eA0 = 0.f, eA1 = 0.f, oA0 = 0.f, oA1 = 0.f;
        float eB0 = 0.f, eB1 = 0.f, oB0 = 0.f, oB1 = 0.f;
#pragma unroll
        for (int kl = 2; kl < 8; kl += 2) {
            float2 t = twA[kl][l];
            eA0 += zA[kl].x * t.x - zA[kl].y * t.y;
            eA1 += zA[kl].z * t.x - zA[kl].w * t.y;
            eB0 += zB[kl].x * t.x - zB[kl].y * t.y;
            eB1 += zB[kl].z * t.x - zB[kl].w * t.y;
        }
#pragma unroll
        for (int kl = 1; kl < 8; kl += 2) {
            float2 t = twA[kl][l];
            oA0 += zA[kl].x * t.x - zA[kl].y * t.y;
            oA1 += zA[kl].z * t.x - zA[kl].w * t.y;
            oB0 += zB[kl].x * t.x - zB[kl].y * t.y;
            oB1 += zB[kl].z * t.x - zB[kl].w * t.y;
        }
        float baseA0 = zAr0 + eA0, baseA1 = zAr1 + eA1;
        float baseB0 = zBr0 + eB0, baseB1 = zBr1 + eB1;
        *(float2*)(opA + l * 64) =
            make_float2((baseA0 + oA0) * sc + a0.x, (baseA1 + oA1) * sc + a0.y);
        *(float2*)(opA + (l + 32) * 64) =
            make_float2((baseA0 - oA0) * sc + a1.x, (baseA1 - oA1) * sc + a1.y);
        *(float2*)(opB + l * 64) =
            make_float2((baseB0 + oB0) * sc + b0.x, (baseB1 + oB1) * sc + b0.y);
        *(float2*)(opB + (l + 32) * 64) =
            make_float2((baseB0 - oB0) * sc + b1.x, (baseB1 - oB1) * sc + b1.y);
    }
}

// ===========================================================================
extern "C" void kernel_launch(void* const* d_in, const int* in_sizes, int n_in,
                              void* d_out, int out_size, void* d_ws, size_t ws_size,
                              hipStream_t stream) {
    const float* x     = (const float*)d_in[0];
    const float* w1    = (const float*)d_in[1];
    const float* b1    = (const float*)d_in[2];
    const float* w2    = (const float*)d_in[3];
    const float* b2    = (const float*)d_in[4];
    const float* la1rA = (const float*)d_in[5];
    const float* la1rB = (const float*)d_in[6];
    const float* la1iA = (const float*)d_in[7];
    const float* la1iB = (const float*)d_in[8];
    const float* la2rA = (const float*)d_in[9];
    const float* la2rB = (const float*)d_in[10];
    const float* la2iA = (const float*)d_in[11];
    const float* la2iB = (const float*)d_in[12];
    float* out = (float*)d_out;

    float* ws = (float*)d_ws;
    float* y1 = ws;                    // [256 bh][8 kl][64 w][32 cp] f4 = 67 MB
    float* y2 = ws + 16777216;         // [4][8][32][64][64] complex = 33 MB
    float* z2 = ws + 25165824;         // same as y2

    hipLaunchKernelGGL(k1a_dft_l, dim3(2048), dim3(256), 0, stream, x, y1);
    hipLaunchKernelGGL(k1b_dft_w, dim3(2048), dim3(256), 0, stream, y1, y2);
    hipLaunchKernelGGL(kc_h_mlp,  dim3(1024), dim3(256), 0, stream, y2, z2,
                       w1, b1, w2, b2, la1rA, la1rB, la1iA, la1iB,
                       la2rA, la2rB, la2iA, la2iB);
    hipLaunchKernelGGL(k3_wl,     dim3(1024), dim3(256), 0, stream, x, z2, out);
}

// Round 10
// 320.479 us; speedup vs baseline: 1.2889x; 1.1305x over previous
//
#include <hip/hip_runtime.h>
#include <math.h>

// ---------------------------------------------------------------------------
// AFNO3D + LoRA, B=4 H=W=L=64 C=64, modes kh<32 kw<32 kl<8, NB=8 BS=8 R=8.
//
// 5-kernel pipeline (intermediates in d_ws):
//   K1a: DFT-L (real->8 modes)   x -> y1[bh][kl][w][c]      (radix-2 folded)
//   K1b: DFT-W (64 -> 32 modes)  y1 -> y2[b][kl][kw][h][c]  (radix-2 folded)
//   K2 : DFT-H + MLP(LoRA) + iDFT-H in LDS                  (radix-2 folded)
//   K3a: iDFT-W (E/O fold)       z2 -> zw[b][h][w][kl][c]
//   K3b: iDFT-L (l/l+32 fold) + residual,  zw,x -> out
//
// R10 change: K3 split in two. R9's single k3 was clean (no spill) but slow:
//   2.7 TB/s, occupancy 19.8% — quarter-channel blocks gave 64-B segments on
//   the 512 MB x/out stream. k3a/k3b keep 32 c-lanes contiguous everywhere
//   (256-512 B segments); zw round-trip (+134 MB) buys 4x wider transactions.
// fp32 throughout. Ortho scaling: 1/512 in K2 (pre-MLP) and 1/512 in K3b.
// ---------------------------------------------------------------------------

#define PI2_64 0.09817477042468103f   // 2*pi/64

__device__ __forceinline__ float gelu_exact(float t) {
    return 0.5f * t * (1.0f + erff(t * 0.7071067811865475f));
}

// ===========================================================================
// K1a: DFT along L (real -> 8 complex modes), radix-2 folded.
// Block = (bh, w8): 256 threads = 8 w x 32 c-pairs. Grid 2048.
// y1 float4 layout: [bh][kl][w][cp]  (cp = c/2; float4 = (re0,im0,re1,im1))
__global__ void __launch_bounds__(256) k1a_dft_l(const float* __restrict__ x,
                                                 float* __restrict__ y1f) {
    __shared__ float2 twT[8][32];        // 2 KB: twT[kl][l] = e(+kl*l/64), l<32
    int tid = threadIdx.x;
    if (tid < 256) {                     // 8*32 = 256 entries
        int k = tid >> 5, l = tid & 31;
        float s, c;
        sincosf(PI2_64 * (float)((k * l) & 63), &s, &c);
        twT[k][l] = make_float2(c, s);
    }
    __syncthreads();

    int bid = blockIdx.x;                // bh*8 + w8
    int w8 = bid & 7, bh = bid >> 3;
    int cp = tid & 31, wl = tid >> 5;
    int w = w8 * 8 + wl;
    const float* xp = x + (size_t)(bh * 64 + w) * 4096 + 2 * cp;

    float4 A[8];
#pragma unroll
    for (int kl = 0; kl < 8; ++kl) A[kl] = make_float4(0.f, 0.f, 0.f, 0.f);

    for (int l0 = 0; l0 < 32; l0 += 2) {
        float2 v0  = *(const float2*)(xp + (l0 + 0) * 64);
        float2 v0p = *(const float2*)(xp + (l0 + 32) * 64);
        float2 v1  = *(const float2*)(xp + (l0 + 1) * 64);
        float2 v1p = *(const float2*)(xp + (l0 + 33) * 64);
        float2 E0 = make_float2(v0.x + v0p.x, v0.y + v0p.y);
        float2 O0 = make_float2(v0.x - v0p.x, v0.y - v0p.y);
        float2 E1 = make_float2(v1.x + v1p.x, v1.y + v1p.y);
        float2 O1 = make_float2(v1.x - v1p.x, v1.y - v1p.y);
#pragma unroll
        for (int kl = 0; kl < 8; ++kl) {
            float2 t0 = twT[kl][l0];
            float2 t1 = twT[kl][l0 + 1];
            float2 s0 = (kl & 1) ? O0 : E0;    // static parity per kl
            float2 s1 = (kl & 1) ? O1 : E1;
            A[kl].x += s0.x * t0.x;  A[kl].y -= s0.x * t0.y;   // * e^{-i th}
            A[kl].z += s0.y * t0.x;  A[kl].w -= s0.y * t0.y;
            A[kl].x += s1.x * t1.x;  A[kl].y -= s1.x * t1.y;
            A[kl].z += s1.y * t1.x;  A[kl].w -= s1.y * t1.y;
        }
    }
    float4* y1 = (float4*)y1f;
    size_t base = (size_t)bh * 16384 + (size_t)w * 32 + cp;
#pragma unroll
    for (int kl = 0; kl < 8; ++kl)
        y1[base + kl * 2048] = A[kl];
}

// ===========================================================================
// K1b: DFT along W (64 -> 32 modes), radix-2 folded.
// Block = (bh, kl), 256 threads. Grid 2048.
__global__ void __launch_bounds__(256) k1b_dft_w(const float* __restrict__ y1f,
                                                 float* __restrict__ y2f) {
    __shared__ float4 sD[64 * 32];       // 32 KB  [w][cp]
    __shared__ float2 twT[32][32];       // 8 KB  twT[kw][w] = e(+kw*w/64), w<32
    int tid = threadIdx.x;
#pragma unroll
    for (int e = 0; e < 4; ++e) {
        int idx = e * 256 + tid;         // 1024 entries
        int k = idx >> 5, l = idx & 31;
        float s, c;
        sincosf(PI2_64 * (float)((k * l) & 63), &s, &c);
        twT[k][l] = make_float2(c, s);
    }
    int pos = blockIdx.x;                // bh*8 + kl
    int kl = pos & 7, bh = pos >> 3;
    const float4* src = (const float4*)y1f + (size_t)pos * 2048;
#pragma unroll
    for (int r = 0; r < 8; ++r)
        sD[r * 256 + tid] = src[r * 256 + tid];
    __syncthreads();

    int cp = tid & 31, kwg = tid >> 5;   // 8 kw-groups of 4
    float4 acc[4];
#pragma unroll
    for (int i = 0; i < 4; ++i) acc[i] = make_float4(0.f, 0.f, 0.f, 0.f);

    for (int w = 0; w < 32; ++w) {
        float4 d  = sD[w * 32 + cp];
        float4 dp = sD[(w + 32) * 32 + cp];
        float4 E = make_float4(d.x + dp.x, d.y + dp.y, d.z + dp.z, d.w + dp.w);
        float4 O = make_float4(d.x - dp.x, d.y - dp.y, d.z - dp.z, d.w - dp.w);
#pragma unroll
        for (int i = 0; i < 4; ++i) {
            float2 t = twT[kwg * 4 + i][w];
            float4 s = (i & 1) ? O : E;        // kw parity = i parity
            acc[i].x += s.x * t.x + s.y * t.y;  // * e^{-i th}
            acc[i].y += s.y * t.x - s.x * t.y;
            acc[i].z += s.z * t.x + s.w * t.y;
            acc[i].w += s.w * t.x - s.z * t.y;
        }
    }
    int b = bh >> 6, h = bh & 63;
    float4* y2 = (float4*)y2f;
#pragma unroll
    for (int i = 0; i < 4; ++i) {
        int kw = kwg * 4 + i;
        y2[((size_t)((b * 8 + kl) * 32 + kw) * 64 + h) * 32 + cp] = acc[i];
    }
}

// ===========================================================================
// K2: fused DFT-H (64->32, *1/512) + block-diag complex MLP + iDFT-H (32->64).
// One block per (b,kw,kl). Radix-2 folded both transforms. Validated R8/R9.
__global__ void __launch_bounds__(256) kc_h_mlp(
        const float* __restrict__ y2f, float* __restrict__ z2f,
        const float* __restrict__ w1, const float* __restrict__ b1,
        const float* __restrict__ w2, const float* __restrict__ b2,
        const float* __restrict__ la1rA, const float* __restrict__ la1rB,
        const float* __restrict__ la1iA, const float* __restrict__ la1iB,
        const float* __restrict__ la2rA, const float* __restrict__ la2rB,
        const float* __restrict__ la2iA, const float* __restrict__ la2iB) {
    __shared__ float2 sD[64][64];      // staged input -> folded E/O; sM2 overlay
    __shared__ float2 sT[32][34];      // 8.7 KB: T(h*kh)= (cos,-sin), h<32 kh<32
    __shared__ float2 sM[32][66];
    __shared__ float  sW[4][512];
    __shared__ float  sb1[128], sb2[128];
    int tid = threadIdx.x;
    int pos = blockIdx.x;              // (b*32+kw)*8 + kl
    int kl = pos & 7, kw = (pos >> 3) & 31, b = pos >> 8;

#pragma unroll
    for (int r = 0; r < 4; ++r) {
        int idx = r * 256 + tid;       // 1024 = 32 h x 32 kh
        int h = idx >> 5, kh = idx & 31;
        float sn, cs;
        sincosf(PI2_64 * (float)((h * kh) & 63), &sn, &cs);
        sT[h][kh] = make_float2(cs, -sn);
    }
    const float2* src = (const float2*)y2f + (size_t)((b * 8 + kl) * 32 + kw) * 4096;
#pragma unroll
    for (int r = 0; r < 8; ++r) {
        int f = r * 512 + tid * 2;
        *(float4*)(&sD[f >> 6][f & 63]) = *(const float4*)(src + f);
    }
    {   // LoRA-corrected weights
        const float* As[4]   = {la1rA, la1iA, la2rA, la2iA};
        const float* Bs[4]   = {la1rB, la1iB, la2rB, la2iB};
        const float* base[4] = {w1, w1 + 512, w2, w2 + 512};
#pragma unroll
        for (int e = 0; e < 8; ++e) {
            int flat = tid + e * 256;
            int mat = flat >> 9;
            int rem = flat & 511;
            int n = rem >> 6, i = (rem >> 3) & 7, o = rem & 7;
            const float* A  = As[mat] + n * 64 + i * 8;
            const float* Bp = Bs[mat] + n * 64 + o;
            float s = 0.f;
#pragma unroll
            for (int r = 0; r < 8; ++r) s += A[r] * Bp[r * 8];
            sW[mat][(i * 8 + o) * 8 + n] = base[mat][n * 64 + i * 8 + o] + 0.125f * s;
        }
        if (tid < 128) sb1[tid] = b1[tid];
        else           sb2[tid - 128] = b2[tid - 128];
    }
    __syncthreads();

    // ---- fold rows in place: sD[h] = D[h]+D[h+32], sD[h+32] = D[h]-D[h+32] --
    {
        float4* sd4 = (float4*)&sD[0][0];   // 64 rows x 32 f4
#pragma unroll
        for (int r = 0; r < 4; ++r) {
            int idx = r * 256 + tid;        // 1024 = 32 h x 32 cq
            int h = idx >> 5, cq = idx & 31;
            float4 a = sd4[h * 32 + cq];
            float4 c = sd4[(h + 32) * 32 + cq];
            sd4[h * 32 + cq]        = make_float4(a.x + c.x, a.y + c.y, a.z + c.z, a.w + c.w);
            sd4[(h + 32) * 32 + cq] = make_float4(a.x - c.x, a.y - c.y, a.z - c.z, a.w - c.w);
        }
    }
    __syncthreads();

    // ---- M[kh][c] = (1/512) * sum_{h<32} T[h][kh] * (E|O)[h][c], 4kh x 2c --
    {
        int kh0 = (tid >> 5) * 4;          // multiple of 4: parity of kh0+i = i&1
        int c0  = (tid & 31) * 2;
        float mr[4][2], mi[4][2];
#pragma unroll
        for (int i = 0; i < 4; ++i)
#pragma unroll
            for (int j = 0; j < 2; ++j) { mr[i][j] = 0.f; mi[i][j] = 0.f; }
        for (int h = 0; h < 32; ++h) {
            float4 dE = *(const float4*)(&sD[h][c0]);        // E rows
            float4 dO = *(const float4*)(&sD[h + 32][c0]);   // O rows
            float Er[2] = {dE.x, dE.z}, Ei[2] = {dE.y, dE.w};
            float Or[2] = {dO.x, dO.z}, Oi[2] = {dO.y, dO.w};
            const float4* tT = (const float4*)(&sT[h][kh0]);
            float4 u0 = tT[0], u1 = tT[1];
            float Tr[4] = {u0.x, u0.z, u1.x, u1.z};
            float Ti[4] = {u0.y, u0.w, u1.y, u1.w};
#pragma unroll
            for (int i = 0; i < 4; ++i) {
                const float* Dr = (i & 1) ? Or : Er;
                const float* Di = (i & 1) ? Oi : Ei;
#pragma unroll
                for (int j = 0; j < 2; ++j) {
                    mr[i][j] += Tr[i] * Dr[j] - Ti[i] * Di[j];
                    mi[i][j] += Tr[i] * Di[j] + Ti[i] * Dr[j];
                }
            }
        }
        const float sc = 1.0f / 512.0f;
#pragma unroll
        for (int i = 0; i < 4; ++i)
#pragma unroll
            for (int j = 0; j < 2; ++j)
                sM[kh0 + i][c0 + j] = make_float2(mr[i][j] * sc, mi[i][j] * sc);
    }
    __syncthreads();

    // ---- MLP per (kh, n) ----
    float2* sM2 = (float2*)&sD[0][0];   // [32][66]
    {
        int kh = tid >> 3, n = tid & 7;
        float xr[8], xi[8];
#pragma unroll
        for (int i = 0; i < 8; ++i) {
            float2 v = sM[kh][n * 8 + i];
            xr[i] = v.x; xi[i] = v.y;
        }
        float o1r[8], o1i[8];
#pragma unroll
        for (int o = 0; o < 8; ++o) {
            float br = sb1[n * 8 + o], bi = sb1[64 + n * 8 + o];
            float sr = br - bi, si = br + bi;
#pragma unroll
            for (int i = 0; i < 8; ++i) {
                float wr = sW[0][(i * 8 + o) * 8 + n];
                float wi = sW[1][(i * 8 + o) * 8 + n];
                sr += xr[i] * wr - xi[i] * wi;
                si += xi[i] * wr + xr[i] * wi;
            }
            o1r[o] = gelu_exact(sr);
            o1i[o] = gelu_exact(si);
        }
#pragma unroll
        for (int o = 0; o < 8; ++o) {
            float br = sb2[n * 8 + o], bi = sb2[64 + n * 8 + o];
            float sr = br - bi, si = br + bi;
#pragma unroll
            for (int i = 0; i < 8; ++i) {
                float wr = sW[2][(i * 8 + o) * 8 + n];
                float wi = sW[3][(i * 8 + o) * 8 + n];
                sr += o1r[i] * wr - o1i[i] * wi;
                si += o1i[i] * wr + o1r[i] * wi;
            }
            sM2[kh * 66 + n * 8 + o] = make_float2(sr, si);
        }
    }
    __syncthreads();

    // ---- iDFT-H folded: out[h]=SE+SO, out[h+32]=SE-SO (2h x 4c tile) ----
    {
        int h0 = (tid >> 4) * 2;           // h0 in {0,2,...,30}
        int c0 = (tid & 15) * 4;
        float SEr[2][4], SEi[2][4], SOr[2][4], SOi[2][4];
#pragma unroll
        for (int r = 0; r < 2; ++r)
#pragma unroll
            for (int j = 0; j < 4; ++j) {
                SEr[r][j] = 0.f; SEi[r][j] = 0.f;
                SOr[r][j] = 0.f; SOi[r][j] = 0.f;
            }
        for (int khp = 0; khp < 16; ++khp) {
#pragma unroll
            for (int par = 0; par < 2; ++par) {
                int kh = 2 * khp + par;
                float2 T0 = sT[h0 + 0][kh];
                float2 T1 = sT[h0 + 1][kh];
                const float4* tM = (const float4*)(sM2 + kh * 66 + c0);
                float4 m0 = tM[0], m1 = tM[1];
                float Mr[4] = {m0.x, m0.z, m1.x, m1.z};
                float Mi[4] = {m0.y, m0.w, m1.y, m1.w};
                float (*Sr)[4] = par ? SOr : SEr;
                float (*Si)[4] = par ? SOi : SEi;
                float Tr[2] = {T0.x, T1.x};
                float Ti[2] = {T0.y, T1.y};
#pragma unroll
                for (int r = 0; r < 2; ++r)
#pragma unroll
                    for (int j = 0; j < 4; ++j) {
                        // conj(T): stored (cos,-sin) -> multiply by (Tr, -Ti)
                        Sr[r][j] += Tr[r] * Mr[j] + Ti[r] * Mi[j];
                        Si[r][j] += Tr[r] * Mi[j] - Ti[r] * Mr[j];
                    }
            }
        }
        float2* dst = (float2*)z2f + (size_t)((b * 8 + kl) * 32 + kw) * 4096;
#pragma unroll
        for (int r = 0; r < 2; ++r) {
            float4* dA = (float4*)(dst + (h0 + r) * 64 + c0);
            dA[0] = make_float4(SEr[r][0] + SOr[r][0], SEi[r][0] + SOi[r][0],
                                SEr[r][1] + SOr[r][1], SEi[r][1] + SOi[r][1]);
            dA[1] = make_float4(SEr[r][2] + SOr[r][2], SEi[r][2] + SOi[r][2],
                                SEr[r][3] + SOr[r][3], SEi[r][3] + SOi[r][3]);
            float4* dB = (float4*)(dst + (h0 + 32 + r) * 64 + c0);
            dB[0] = make_float4(SEr[r][0] - SOr[r][0], SEi[r][0] - SOi[r][0],
                                SEr[r][1] - SOr[r][1], SEi[r][1] - SOi[r][1]);
            dB[1] = make_float4(SEr[r][2] - SOr[r][2], SEi[r][2] - SOi[r][2],
                                SEr[r][3] - SOr[r][3], SEi[r][3] - SOi[r][3]);
        }
    }
}

// ===========================================================================
// K3a: iDFT along W (32 modes -> 64), even/odd-kw fold.
// Block = (b, h, klq in [0,4)): 256 threads = 32 cp x 8 wq. Grid 1024.
// Stages z2 [2 kl][32 kw][32 cp] (32 KB). Thread handles w' = wq*4+j (j<4)
// and w'+32 via fold, for 2 kl values. Writes zw[b][h][w][kl][cp] (f4).
__global__ void __launch_bounds__(256) k3a_idft_w(const float* __restrict__ z2f,
                                                  float* __restrict__ zwf) {
    __shared__ float4 sZ[2 * 32 * 32];   // 32 KB  [kli][kw][cp]
    __shared__ float2 twT[32][32];       // 8 KB   twT[w][kw] = e(+kw*w/64), w<32
    int tid = threadIdx.x;
#pragma unroll
    for (int e = 0; e < 4; ++e) {
        int idx = e * 256 + tid;         // 1024 entries
        int w = idx >> 5, kw = idx & 31;
        float s, c;
        sincosf(PI2_64 * (float)((w * kw) & 63), &s, &c);
        twT[w][kw] = make_float2(c, s);
    }
    int bid = blockIdx.x;                // (b*64+h)*4 + klq
    int klq = bid & 3, h = (bid >> 2) & 63, b = bid >> 8;
    const float4* z2 = (const float4*)z2f;
#pragma unroll
    for (int r = 0; r < 8; ++r) {
        int idx = r * 256 + tid;         // 0..2047 = (kli*32+kw)*32 + cp
        int row = idx >> 5, cp2 = idx & 31;
        int kli = row >> 5, kw = row & 31;
        sZ[idx] = z2[((size_t)((b * 8 + klq * 2 + kli) * 32 + kw) * 64 + h) * 32 + cp2];
    }
    __syncthreads();

    int cp = tid & 31, wq = tid >> 5;    // wq in [0,8)

    float4 E[2][4], O[2][4];
#pragma unroll
    for (int kli = 0; kli < 2; ++kli)
#pragma unroll
        for (int j = 0; j < 4; ++j) {
            E[kli][j] = make_float4(0.f, 0.f, 0.f, 0.f);
            O[kli][j] = make_float4(0.f, 0.f, 0.f, 0.f);
        }

    for (int kw = 0; kw < 32; kw += 2) {
        // even kw -> E
#pragma unroll
        for (int kli = 0; kli < 2; ++kli) {
            float4 d = sZ[(kli * 32 + kw) * 32 + cp];
#pragma unroll
            for (int j = 0; j < 4; ++j) {
                float2 t = twT[wq * 4 + j][kw];
                E[kli][j].x += d.x * t.x - d.y * t.y;
                E[kli][j].y += d.y * t.x + d.x * t.y;
                E[kli][j].z += d.z * t.x - d.w * t.y;
                E[kli][j].w += d.w * t.x + d.z * t.y;
            }
        }
        // odd kw -> O
#pragma unroll
        for (int kli = 0; kli < 2; ++kli) {
            float4 d = sZ[(kli * 32 + kw + 1) * 32 + cp];
#pragma unroll
            for (int j = 0; j < 4; ++j) {
                float2 t = twT[wq * 4 + j][kw + 1];
                O[kli][j].x += d.x * t.x - d.y * t.y;
                O[kli][j].y += d.y * t.x + d.x * t.y;
                O[kli][j].z += d.z * t.x - d.w * t.y;
                O[kli][j].w += d.w * t.x + d.z * t.y;
            }
        }
    }
    // zw rows: w = wq*4+j gets E+O; w+32 gets E-O.
    float4* zw = (float4*)zwf;
    size_t slab = ((size_t)(b * 64 + h)) * 16384;   // 64 w * 8 kl * 32 cp f4
#pragma unroll
    for (int kli = 0; kli < 2; ++kli) {
        int kl = klq * 2 + kli;
#pragma unroll
        for (int j = 0; j < 4; ++j) {
            int w = wq * 4 + j;
            float4 e = E[kli][j], o = O[kli][j];
            zw[slab + ((size_t)w * 8 + kl) * 32 + cp] =
                make_float4(e.x + o.x, e.y + o.y, e.z + o.z, e.w + o.w);
            zw[slab + ((size_t)(w + 32) * 8 + kl) * 32 + cp] =
                make_float4(e.x - o.x, e.y - o.y, e.z - o.z, e.w - o.w);
        }
    }
}

// ===========================================================================
// K3b: iDFT along L (numpy irfft: Im(kl=0) dropped, modes 1..7 doubled),
// l/l+32 folded, + residual. Block = (b, h, w8): 256 threads = 8 w x 32 cp.
// Grid 2048. zw reads contiguous; x/out 256-B row segments.
__global__ void __launch_bounds__(256) k3b_idft_l(const float* __restrict__ x,
                                                  const float* __restrict__ zwf,
                                                  float* __restrict__ outp) {
    __shared__ float2 twA[8][32];        // 1 KB: twA[k][l] = e(+k*l/64), l<32
    int tid = threadIdx.x;
    if (tid < 256) {
        int k = tid >> 5, l = tid & 31;
        float s, c;
        sincosf(PI2_64 * (float)((k * l) & 63), &s, &c);
        twA[k][l] = make_float2(c, s);
    }
    __syncthreads();

    int bid = blockIdx.x;                // (b*64+h)*8 + w8
    int w8 = bid & 7, bh = bid >> 3;
    int cp = tid & 31, wl = tid >> 5;
    int w = w8 * 8 + wl;

    const float4* zw = (const float4*)zwf +
        ((size_t)bh * 64 + w) * 256 + cp;   // [kl]*32 stride
    float4 z[8];
#pragma unroll
    for (int kl = 0; kl < 8; ++kl) z[kl] = zw[kl * 32];

    float z0r0 = z[0].x, z0r1 = z[0].z;
#pragma unroll
    for (int kl = 1; kl < 8; ++kl) {     // pre-double modes 1..7
        z[kl].x *= 2.f; z[kl].y *= 2.f; z[kl].z *= 2.f; z[kl].w *= 2.f;
    }
    const size_t row = ((size_t)(bh * 64 + w)) * 4096;
    const float* xp = x + row + 2 * cp;
    float* op = outp + row + 2 * cp;
    const float sc = 1.0f / 512.0f;

    for (int l = 0; l < 32; ++l) {
        float2 a0 = *(const float2*)(xp + l * 64);
        float2 a1 = *(const float2*)(xp + (l + 32) * 64);
        float e0 = 0.f, e1 = 0.f, o0 = 0.f, o1 = 0.f;
#pragma unroll
        for (int kl = 2; kl < 8; kl += 2) {
            float2 t = twA[kl][l];
            e0 += z[kl].x * t.x - z[kl].y * t.y;
            e1 += z[kl].z * t.x - z[kl].w * t.y;
        }
#pragma unroll
        for (int kl = 1; kl < 8; kl += 2) {
            float2 t = twA[kl][l];
            o0 += z[kl].x * t.x - z[kl].y * t.y;
            o1 += z[kl].z * t.x - z[kl].w * t.y;
        }
        float base0 = z0r0 + e0, base1 = z0r1 + e1;
        *(float2*)(op + l * 64) =
            make_float2((base0 + o0) * sc + a0.x, (base1 + o1) * sc + a0.y);
        *(float2*)(op + (l + 32) * 64) =
            make_float2((base0 - o0) * sc + a1.x, (base1 - o1) * sc + a1.y);
    }
}

// ===========================================================================
extern "C" void kernel_launch(void* const* d_in, const int* in_sizes, int n_in,
                              void* d_out, int out_size, void* d_ws, size_t ws_size,
                              hipStream_t stream) {
    const float* x     = (const float*)d_in[0];
    const float* w1    = (const float*)d_in[1];
    const float* b1    = (const float*)d_in[2];
    const float* w2    = (const float*)d_in[3];
    const float* b2    = (const float*)d_in[4];
    const float* la1rA = (const float*)d_in[5];
    const float* la1rB = (const float*)d_in[6];
    const float* la1iA = (const float*)d_in[7];
    const float* la1iB = (const float*)d_in[8];
    const float* la2rA = (const float*)d_in[9];
    const float* la2rB = (const float*)d_in[10];
    const float* la2iA = (const float*)d_in[11];
    const float* la2iB = (const float*)d_in[12];
    float* out = (float*)d_out;

    float* ws = (float*)d_ws;
    float* y1 = ws;                    // 16777216 floats (67 MB)
    float* y2 = ws + 16777216;         // 8388608 floats (33 MB)
    float* z2 = ws + 25165824;         // 8388608 floats (33 MB)
    float* zw = ws + 33554432;         // 16777216 floats (67 MB)

    hipLaunchKernelGGL(k1a_dft_l,  dim3(2048), dim3(256), 0, stream, x, y1);
    hipLaunchKernelGGL(k1b_dft_w,  dim3(2048), dim3(256), 0, stream, y1, y2);
    hipLaunchKernelGGL(kc_h_mlp,   dim3(1024), dim3(256), 0, stream, y2, z2,
                       w1, b1, w2, b2, la1rA, la1rB, la1iA, la1iB,
                       la2rA, la2rB, la2iA, la2iB);
    hipLaunchKernelGGL(k3a_idft_w, dim3(1024), dim3(256), 0, stream, z2, zw);
    hipLaunchKernelGGL(k3b_idft_l, dim3(2048), dim3(256), 0, stream, x, zw, out);
}

// Round 11
// 300.581 us; speedup vs baseline: 1.3742x; 1.0662x over previous
//
#include <hip/hip_runtime.h>
#include <math.h>

// ---------------------------------------------------------------------------
// AFNO3D + LoRA, B=4 H=W=L=64 C=64, modes kh<32 kw<32 kl<8, NB=8 BS=8 R=8.
//
// 5-kernel pipeline (intermediates in d_ws, ALL bf16-packed):
//   K1a: DFT-L (real->8 modes)   x -> y1[bh][kl][w][cp]     (radix-2 folded)
//   K1b: DFT-W (64 -> 32 modes)  y1 -> y2[b][kl][kw][h][cp] (radix-2 folded)
//   K2 : DFT-H + MLP(LoRA) + iDFT-H in LDS                  (radix-2 folded)
//   K3a: iDFT-W (E/O fold)       z2 -> zw[bh][w][kl][cp]
//   K3b: iDFT-L (l/l+32 fold) + residual,  zw,x -> out
//
// R11 change: intermediates y1/y2/z2/zw stored as bf16 (uint2 = 4 bf16 =
//   2 complex). Halves the 402 MB intermediate round-trip traffic; noise
//   (~0.2% rel, RNE) is attenuated by the 1/512 ortho scales + small MLP
//   weights to ~1e-5 at the output (budget 0.109). All inner compute loops
//   unchanged from validated R10 (LDS staging unpacks to fp32).
// x/out remain fp32. Ortho scaling: 1/512 in K2 (pre-MLP) and 1/512 in K3b.
// ---------------------------------------------------------------------------

#define PI2_64 0.09817477042468103f   // 2*pi/64

__device__ __forceinline__ float gelu_exact(float t) {
    return 0.5f * t * (1.0f + erff(t * 0.7071067811865475f));
}

// ---- bf16 pack/unpack (RNE round; unpack = pure bit ops) ----
__device__ __forceinline__ unsigned int f2bf(float f) {
    unsigned int u = __float_as_uint(f);
    return (u + 0x7FFFu + ((u >> 16) & 1u)) >> 16;
}
__device__ __forceinline__ uint2 pack4(float4 f) {
    return make_uint2(f2bf(f.x) | (f2bf(f.y) << 16),
                      f2bf(f.z) | (f2bf(f.w) << 16));
}
__device__ __forceinline__ float4 unpack4(uint2 u) {
    return make_float4(__uint_as_float(u.x << 16),
                       __uint_as_float(u.x & 0xFFFF0000u),
                       __uint_as_float(u.y << 16),
                       __uint_as_float(u.y & 0xFFFF0000u));
}

// ===========================================================================
// K1a: DFT along L (real -> 8 complex modes), radix-2 folded.
// Block = (bh, w8): 256 threads = 8 w x 32 c-pairs. Grid 2048.
// y1 uint2 layout: [bh][kl][w][cp]  (cp = c/2; 4 bf16 = (re0,im0,re1,im1))
__global__ void __launch_bounds__(256) k1a_dft_l(const float* __restrict__ x,
                                                 unsigned int* __restrict__ y1f) {
    __shared__ float2 twT[8][32];        // 2 KB: twT[kl][l] = e(+kl*l/64), l<32
    int tid = threadIdx.x;
    if (tid < 256) {
        int k = tid >> 5, l = tid & 31;
        float s, c;
        sincosf(PI2_64 * (float)((k * l) & 63), &s, &c);
        twT[k][l] = make_float2(c, s);
    }
    __syncthreads();

    int bid = blockIdx.x;                // bh*8 + w8
    int w8 = bid & 7, bh = bid >> 3;
    int cp = tid & 31, wl = tid >> 5;
    int w = w8 * 8 + wl;
    const float* xp = x + (size_t)(bh * 64 + w) * 4096 + 2 * cp;

    float4 A[8];
#pragma unroll
    for (int kl = 0; kl < 8; ++kl) A[kl] = make_float4(0.f, 0.f, 0.f, 0.f);

    for (int l0 = 0; l0 < 32; l0 += 2) {
        float2 v0  = *(const float2*)(xp + (l0 + 0) * 64);
        float2 v0p = *(const float2*)(xp + (l0 + 32) * 64);
        float2 v1  = *(const float2*)(xp + (l0 + 1) * 64);
        float2 v1p = *(const float2*)(xp + (l0 + 33) * 64);
        float2 E0 = make_float2(v0.x + v0p.x, v0.y + v0p.y);
        float2 O0 = make_float2(v0.x - v0p.x, v0.y - v0p.y);
        float2 E1 = make_float2(v1.x + v1p.x, v1.y + v1p.y);
        float2 O1 = make_float2(v1.x - v1p.x, v1.y - v1p.y);
#pragma unroll
        for (int kl = 0; kl < 8; ++kl) {
            float2 t0 = twT[kl][l0];
            float2 t1 = twT[kl][l0 + 1];
            float2 s0 = (kl & 1) ? O0 : E0;    // static parity per kl
            float2 s1 = (kl & 1) ? O1 : E1;
            A[kl].x += s0.x * t0.x;  A[kl].y -= s0.x * t0.y;   // * e^{-i th}
            A[kl].z += s0.y * t0.x;  A[kl].w -= s0.y * t0.y;
            A[kl].x += s1.x * t1.x;  A[kl].y -= s1.x * t1.y;
            A[kl].z += s1.y * t1.x;  A[kl].w -= s1.y * t1.y;
        }
    }
    uint2* y1 = (uint2*)y1f;
    size_t base = (size_t)bh * 16384 + (size_t)w * 32 + cp;
#pragma unroll
    for (int kl = 0; kl < 8; ++kl)
        y1[base + kl * 2048] = pack4(A[kl]);
}

// ===========================================================================
// K1b: DFT along W (64 -> 32 modes), radix-2 folded.
// Block = (bh, kl), 256 threads. Grid 2048. Stages bf16 slab -> fp32 LDS.
__global__ void __launch_bounds__(256) k1b_dft_w(const unsigned int* __restrict__ y1f,
                                                 unsigned int* __restrict__ y2f) {
    __shared__ float4 sD[64 * 32];       // 32 KB  [w][cp]
    __shared__ float2 twT[32][32];       // 8 KB  twT[kw][w] = e(+kw*w/64), w<32
    int tid = threadIdx.x;
#pragma unroll
    for (int e = 0; e < 4; ++e) {
        int idx = e * 256 + tid;         // 1024 entries
        int k = idx >> 5, l = idx & 31;
        float s, c;
        sincosf(PI2_64 * (float)((k * l) & 63), &s, &c);
        twT[k][l] = make_float2(c, s);
    }
    int pos = blockIdx.x;                // bh*8 + kl
    int kl = pos & 7, bh = pos >> 3;
    const uint2* src = (const uint2*)y1f + (size_t)pos * 2048;
#pragma unroll
    for (int r = 0; r < 8; ++r)
        sD[r * 256 + tid] = unpack4(src[r * 256 + tid]);
    __syncthreads();

    int cp = tid & 31, kwg = tid >> 5;   // 8 kw-groups of 4
    float4 acc[4];
#pragma unroll
    for (int i = 0; i < 4; ++i) acc[i] = make_float4(0.f, 0.f, 0.f, 0.f);

    for (int w = 0; w < 32; ++w) {
        float4 d  = sD[w * 32 + cp];
        float4 dp = sD[(w + 32) * 32 + cp];
        float4 E = make_float4(d.x + dp.x, d.y + dp.y, d.z + dp.z, d.w + dp.w);
        float4 O = make_float4(d.x - dp.x, d.y - dp.y, d.z - dp.z, d.w - dp.w);
#pragma unroll
        for (int i = 0; i < 4; ++i) {
            float2 t = twT[kwg * 4 + i][w];
            float4 s = (i & 1) ? O : E;        // kw parity = i parity
            acc[i].x += s.x * t.x + s.y * t.y;  // * e^{-i th}
            acc[i].y += s.y * t.x - s.x * t.y;
            acc[i].z += s.z * t.x + s.w * t.y;
            acc[i].w += s.w * t.x - s.z * t.y;
        }
    }
    int b = bh >> 6, h = bh & 63;
    uint2* y2 = (uint2*)y2f;
#pragma unroll
    for (int i = 0; i < 4; ++i) {
        int kw = kwg * 4 + i;
        y2[((size_t)((b * 8 + kl) * 32 + kw) * 64 + h) * 32 + cp] = pack4(acc[i]);
    }
}

// ===========================================================================
// K2: fused DFT-H (64->32, *1/512) + block-diag complex MLP + iDFT-H (32->64).
// One block per (b,kw,kl). Radix-2 folded both transforms. bf16 I/O.
__global__ void __launch_bounds__(256) kc_h_mlp(
        const unsigned int* __restrict__ y2f, unsigned int* __restrict__ z2f,
        const float* __restrict__ w1, const float* __restrict__ b1,
        const float* __restrict__ w2, const float* __restrict__ b2,
        const float* __restrict__ la1rA, const float* __restrict__ la1rB,
        const float* __restrict__ la1iA, const float* __restrict__ la1iB,
        const float* __restrict__ la2rA, const float* __restrict__ la2rB,
        const float* __restrict__ la2iA, const float* __restrict__ la2iB) {
    __shared__ float2 sD[64][64];      // staged input -> folded E/O; sM2 overlay
    __shared__ float2 sT[32][34];      // 8.7 KB: T(h*kh)= (cos,-sin), h<32 kh<32
    __shared__ float2 sM[32][66];
    __shared__ float  sW[4][512];
    __shared__ float  sb1[128], sb2[128];
    int tid = threadIdx.x;
    int pos = blockIdx.x;              // (b*32+kw)*8 + kl
    int kl = pos & 7, kw = (pos >> 3) & 31, b = pos >> 8;

#pragma unroll
    for (int r = 0; r < 4; ++r) {
        int idx = r * 256 + tid;       // 1024 = 32 h x 32 kh
        int h = idx >> 5, kh = idx & 31;
        float sn, cs;
        sincosf(PI2_64 * (float)((h * kh) & 63), &sn, &cs);
        sT[h][kh] = make_float2(cs, -sn);
    }
    const uint2* src = (const uint2*)y2f + (size_t)((b * 8 + kl) * 32 + kw) * 2048;
#pragma unroll
    for (int r = 0; r < 8; ++r) {
        int idx = r * 256 + tid;       // 0..2047: h = idx>>5, cpair = idx&31
        *(float4*)(&sD[idx >> 5][(idx & 31) * 2]) = unpack4(src[idx]);
    }
    {   // LoRA-corrected weights
        const float* As[4]   = {la1rA, la1iA, la2rA, la2iA};
        const float* Bs[4]   = {la1rB, la1iB, la2rB, la2iB};
        const float* base[4] = {w1, w1 + 512, w2, w2 + 512};
#pragma unroll
        for (int e = 0; e < 8; ++e) {
            int flat = tid + e * 256;
            int mat = flat >> 9;
            int rem = flat & 511;
            int n = rem >> 6, i = (rem >> 3) & 7, o = rem & 7;
            const float* A  = As[mat] + n * 64 + i * 8;
            const float* Bp = Bs[mat] + n * 64 + o;
            float s = 0.f;
#pragma unroll
            for (int r = 0; r < 8; ++r) s += A[r] * Bp[r * 8];
            sW[mat][(i * 8 + o) * 8 + n] = base[mat][n * 64 + i * 8 + o] + 0.125f * s;
        }
        if (tid < 128) sb1[tid] = b1[tid];
        else           sb2[tid - 128] = b2[tid - 128];
    }
    __syncthreads();

    // ---- fold rows in place: sD[h] = D[h]+D[h+32], sD[h+32] = D[h]-D[h+32] --
    {
        float4* sd4 = (float4*)&sD[0][0];   // 64 rows x 32 f4
#pragma unroll
        for (int r = 0; r < 4; ++r) {
            int idx = r * 256 + tid;        // 1024 = 32 h x 32 cq
            int h = idx >> 5, cq = idx & 31;
            float4 a = sd4[h * 32 + cq];
            float4 c = sd4[(h + 32) * 32 + cq];
            sd4[h * 32 + cq]        = make_float4(a.x + c.x, a.y + c.y, a.z + c.z, a.w + c.w);
            sd4[(h + 32) * 32 + cq] = make_float4(a.x - c.x, a.y - c.y, a.z - c.z, a.w - c.w);
        }
    }
    __syncthreads();

    // ---- M[kh][c] = (1/512) * sum_{h<32} T[h][kh] * (E|O)[h][c], 4kh x 2c --
    {
        int kh0 = (tid >> 5) * 4;          // multiple of 4: parity of kh0+i = i&1
        int c0  = (tid & 31) * 2;
        float mr[4][2], mi[4][2];
#pragma unroll
        for (int i = 0; i < 4; ++i)
#pragma unroll
            for (int j = 0; j < 2; ++j) { mr[i][j] = 0.f; mi[i][j] = 0.f; }
        for (int h = 0; h < 32; ++h) {
            float4 dE = *(const float4*)(&sD[h][c0]);        // E rows
            float4 dO = *(const float4*)(&sD[h + 32][c0]);   // O rows
            float Er[2] = {dE.x, dE.z}, Ei[2] = {dE.y, dE.w};
            float Or[2] = {dO.x, dO.z}, Oi[2] = {dO.y, dO.w};
            const float4* tT = (const float4*)(&sT[h][kh0]);
            float4 u0 = tT[0], u1 = tT[1];
            float Tr[4] = {u0.x, u0.z, u1.x, u1.z};
            float Ti[4] = {u0.y, u0.w, u1.y, u1.w};
#pragma unroll
            for (int i = 0; i < 4; ++i) {
                const float* Dr = (i & 1) ? Or : Er;
                const float* Di = (i & 1) ? Oi : Ei;
#pragma unroll
                for (int j = 0; j < 2; ++j) {
                    mr[i][j] += Tr[i] * Dr[j] - Ti[i] * Di[j];
                    mi[i][j] += Tr[i] * Di[j] + Ti[i] * Dr[j];
                }
            }
        }
        const float sc = 1.0f / 512.0f;
#pragma unroll
        for (int i = 0; i < 4; ++i)
#pragma unroll
            for (int j = 0; j < 2; ++j)
                sM[kh0 + i][c0 + j] = make_float2(mr[i][j] * sc, mi[i][j] * sc);
    }
    __syncthreads();

    // ---- MLP per (kh, n) ----
    float2* sM2 = (float2*)&sD[0][0];   // [32][66]
    {
        int kh = tid >> 3, n = tid & 7;
        float xr[8], xi[8];
#pragma unroll
        for (int i = 0; i < 8; ++i) {
            float2 v = sM[kh][n * 8 + i];
            xr[i] = v.x; xi[i] = v.y;
        }
        float o1r[8], o1i[8];
#pragma unroll
        for (int o = 0; o < 8; ++o) {
            float br = sb1[n * 8 + o], bi = sb1[64 + n * 8 + o];
            float sr = br - bi, si = br + bi;
#pragma unroll
            for (int i = 0; i < 8; ++i) {
                float wr = sW[0][(i * 8 + o) * 8 + n];
                float wi = sW[1][(i * 8 + o) * 8 + n];
                sr += xr[i] * wr - xi[i] * wi;
                si += xi[i] * wr + xr[i] * wi;
            }
            o1r[o] = gelu_exact(sr);
            o1i[o] = gelu_exact(si);
        }
#pragma unroll
        for (int o = 0; o < 8; ++o) {
            float br = sb2[n * 8 + o], bi = sb2[64 + n * 8 + o];
            float sr = br - bi, si = br + bi;
#pragma unroll
            for (int i = 0; i < 8; ++i) {
                float wr = sW[2][(i * 8 + o) * 8 + n];
                float wi = sW[3][(i * 8 + o) * 8 + n];
                sr += o1r[i] * wr - o1i[i] * wi;
                si += o1i[i] * wr + o1r[i] * wi;
            }
            sM2[kh * 66 + n * 8 + o] = make_float2(sr, si);
        }
    }
    __syncthreads();

    // ---- iDFT-H folded: out[h]=SE+SO, out[h+32]=SE-SO (2h x 4c tile) ----
    {
        int h0 = (tid >> 4) * 2;           // h0 in {0,2,...,30}
        int c0 = (tid & 15) * 4;
        float SEr[2][4], SEi[2][4], SOr[2][4], SOi[2][4];
#pragma unroll
        for (int r = 0; r < 2; ++r)
#pragma unroll
            for (int j = 0; j < 4; ++j) {
                SEr[r][j] = 0.f; SEi[r][j] = 0.f;
                SOr[r][j] = 0.f; SOi[r][j] = 0.f;
            }
        for (int khp = 0; khp < 16; ++khp) {
#pragma unroll
            for (int par = 0; par < 2; ++par) {
                int kh = 2 * khp + par;
                float2 T0 = sT[h0 + 0][kh];
                float2 T1 = sT[h0 + 1][kh];
                const float4* tM = (const float4*)(sM2 + kh * 66 + c0);
                float4 m0 = tM[0], m1 = tM[1];
                float Mr[4] = {m0.x, m0.z, m1.x, m1.z};
                float Mi[4] = {m0.y, m0.w, m1.y, m1.w};
                float (*Sr)[4] = par ? SOr : SEr;
                float (*Si)[4] = par ? SOi : SEi;
                float Tr[2] = {T0.x, T1.x};
                float Ti[2] = {T0.y, T1.y};
#pragma unroll
                for (int r = 0; r < 2; ++r)
#pragma unroll
                    for (int j = 0; j < 4; ++j) {
                        // conj(T): stored (cos,-sin) -> multiply by (Tr, -Ti)
                        Sr[r][j] += Tr[r] * Mr[j] + Ti[r] * Mi[j];
                        Si[r][j] += Tr[r] * Mi[j] - Ti[r] * Mr[j];
                    }
            }
        }
        uint2* dst = (uint2*)z2f + (size_t)((b * 8 + kl) * 32 + kw) * 2048;
#pragma unroll
        for (int r = 0; r < 2; ++r) {
            // rows h0+r and h0+32+r; uint2 index = h*32 + c0/2 (+0,+1)
            int iA = (h0 + r) * 32 + (c0 >> 1);
            dst[iA]     = pack4(make_float4(SEr[r][0] + SOr[r][0], SEi[r][0] + SOi[r][0],
                                            SEr[r][1] + SOr[r][1], SEi[r][1] + SOi[r][1]));
            dst[iA + 1] = pack4(make_float4(SEr[r][2] + SOr[r][2], SEi[r][2] + SOi[r][2],
                                            SEr[r][3] + SOr[r][3], SEi[r][3] + SOi[r][3]));
            int iB = (h0 + 32 + r) * 32 + (c0 >> 1);
            dst[iB]     = pack4(make_float4(SEr[r][0] - SOr[r][0], SEi[r][0] - SOi[r][0],
                                            SEr[r][1] - SOr[r][1], SEi[r][1] - SOi[r][1]));
            dst[iB + 1] = pack4(make_float4(SEr[r][2] - SOr[r][2], SEi[r][2] - SOi[r][2],
                                            SEr[r][3] - SOr[r][3], SEi[r][3] - SOi[r][3]));
        }
    }
}

// ===========================================================================
// K3a: iDFT along W (32 modes -> 64), even/odd-kw fold. bf16 I/O.
// Block = (b, h, klq in [0,4)): 256 threads = 32 cp x 8 wq. Grid 1024.
__global__ void __launch_bounds__(256) k3a_idft_w(const unsigned int* __restrict__ z2f,
                                                  unsigned int* __restrict__ zwf) {
    __shared__ float4 sZ[2 * 32 * 32];   // 32 KB  [kli][kw][cp]
    __shared__ float2 twT[32][32];       // 8 KB   twT[w][kw] = e(+kw*w/64), w<32
    int tid = threadIdx.x;
#pragma unroll
    for (int e = 0; e < 4; ++e) {
        int idx = e * 256 + tid;         // 1024 entries
        int w = idx >> 5, kw = idx & 31;
        float s, c;
        sincosf(PI2_64 * (float)((w * kw) & 63), &s, &c);
        twT[w][kw] = make_float2(c, s);
    }
    int bid = blockIdx.x;                // (b*64+h)*4 + klq
    int klq = bid & 3, h = (bid >> 2) & 63, b = bid >> 8;
    const uint2* z2 = (const uint2*)z2f;
#pragma unroll
    for (int r = 0; r < 8; ++r) {
        int idx = r * 256 + tid;         // 0..2047 = (kli*32+kw)*32 + cp
        int row = idx >> 5, cp2 = idx & 31;
        int kli = row >> 5, kw = row & 31;
        sZ[idx] = unpack4(
            z2[((size_t)((b * 8 + klq * 2 + kli) * 32 + kw) * 64 + h) * 32 + cp2]);
    }
    __syncthreads();

    int cp = tid & 31, wq = tid >> 5;    // wq in [0,8)

    float4 E[2][4], O[2][4];
#pragma unroll
    for (int kli = 0; kli < 2; ++kli)
#pragma unroll
        for (int j = 0; j < 4; ++j) {
            E[kli][j] = make_float4(0.f, 0.f, 0.f, 0.f);
            O[kli][j] = make_float4(0.f, 0.f, 0.f, 0.f);
        }

    for (int kw = 0; kw < 32; kw += 2) {
#pragma unroll
        for (int kli = 0; kli < 2; ++kli) {
            float4 d = sZ[(kli * 32 + kw) * 32 + cp];
#pragma unroll
            for (int j = 0; j < 4; ++j) {
                float2 t = twT[wq * 4 + j][kw];
                E[kli][j].x += d.x * t.x - d.y * t.y;
                E[kli][j].y += d.y * t.x + d.x * t.y;
                E[kli][j].z += d.z * t.x - d.w * t.y;
                E[kli][j].w += d.w * t.x + d.z * t.y;
            }
        }
#pragma unroll
        for (int kli = 0; kli < 2; ++kli) {
            float4 d = sZ[(kli * 32 + kw + 1) * 32 + cp];
#pragma unroll
            for (int j = 0; j < 4; ++j) {
                float2 t = twT[wq * 4 + j][kw + 1];
                O[kli][j].x += d.x * t.x - d.y * t.y;
                O[kli][j].y += d.y * t.x + d.x * t.y;
                O[kli][j].z += d.z * t.x - d.w * t.y;
                O[kli][j].w += d.w * t.x + d.z * t.y;
            }
        }
    }
    uint2* zw = (uint2*)zwf;
    size_t slab = ((size_t)(b * 64 + h)) * 16384;   // 64w * 8kl * 32cp uint2
#pragma unroll
    for (int kli = 0; kli < 2; ++kli) {
        int kl = klq * 2 + kli;
#pragma unroll
        for (int j = 0; j < 4; ++j) {
            int w = wq * 4 + j;
            float4 e = E[kli][j], o = O[kli][j];
            zw[slab + ((size_t)w * 8 + kl) * 32 + cp] =
                pack4(make_float4(e.x + o.x, e.y + o.y, e.z + o.z, e.w + o.w));
            zw[slab + ((size_t)(w + 32) * 8 + kl) * 32 + cp] =
                pack4(make_float4(e.x - o.x, e.y - o.y, e.z - o.z, e.w - o.w));
        }
    }
}

// ===========================================================================
// K3b: iDFT along L (numpy irfft: Im(kl=0) dropped, modes 1..7 doubled),
// l/l+32 folded, + residual. Block = (b, h, w8): 256 threads = 8 w x 32 cp.
// Grid 2048. zw bf16 reads; x/out fp32 256-B row segments.
__global__ void __launch_bounds__(256) k3b_idft_l(const float* __restrict__ x,
                                                  const unsigned int* __restrict__ zwf,
                                                  float* __restrict__ outp) {
    __shared__ float2 twA[8][32];        // 1 KB: twA[k][l] = e(+k*l/64), l<32
    int tid = threadIdx.x;
    if (tid < 256) {
        int k = tid >> 5, l = tid & 31;
        float s, c;
        sincosf(PI2_64 * (float)((k * l) & 63), &s, &c);
        twA[k][l] = make_float2(c, s);
    }
    __syncthreads();

    int bid = blockIdx.x;                // (b*64+h)*8 + w8
    int w8 = bid & 7, bh = bid >> 3;
    int cp = tid & 31, wl = tid >> 5;
    int w = w8 * 8 + wl;

    const uint2* zw = (const uint2*)zwf + ((size_t)bh * 64 + w) * 256 + cp;
    float4 z[8];
#pragma unroll
    for (int kl = 0; kl < 8; ++kl) z[kl] = unpack4(zw[kl * 32]);

    float z0r0 = z[0].x, z0r1 = z[0].z;
#pragma unroll
    for (int kl = 1; kl < 8; ++kl) {     // pre-double modes 1..7
        z[kl].x *= 2.f; z[kl].y *= 2.f; z[kl].z *= 2.f; z[kl].w *= 2.f;
    }
    const size_t row = ((size_t)(bh * 64 + w)) * 4096;
    const float* xp = x + row + 2 * cp;
    float* op = outp + row + 2 * cp;
    const float sc = 1.0f / 512.0f;

    for (int l = 0; l < 32; ++l) {
        float2 a0 = *(const float2*)(xp + l * 64);
        float2 a1 = *(const float2*)(xp + (l + 32) * 64);
        float e0 = 0.f, e1 = 0.f, o0 = 0.f, o1 = 0.f;
#pragma unroll
        for (int kl = 2; kl < 8; kl += 2) {
            float2 t = twA[kl][l];
            e0 += z[kl].x * t.x - z[kl].y * t.y;
            e1 += z[kl].z * t.x - z[kl].w * t.y;
        }
#pragma unroll
        for (int kl = 1; kl < 8; kl += 2) {
            float2 t = twA[kl][l];
            o0 += z[kl].x * t.x - z[kl].y * t.y;
            o1 += z[kl].z * t.x - z[kl].w * t.y;
        }
        float base0 = z0r0 + e0, base1 = z0r1 + e1;
        *(float2*)(op + l * 64) =
            make_float2((base0 + o0) * sc + a0.x, (base1 + o1) * sc + a0.y);
        *(float2*)(op + (l + 32) * 64) =
            make_float2((base0 - o0) * sc + a1.x, (base1 - o1) * sc + a1.y);
    }
}

// ===========================================================================
extern "C" void kernel_launch(void* const* d_in, const int* in_sizes, int n_in,
                              void* d_out, int out_size, void* d_ws, size_t ws_size,
                              hipStream_t stream) {
    const float* x     = (const float*)d_in[0];
    const float* w1    = (const float*)d_in[1];
    const float* b1    = (const float*)d_in[2];
    const float* w2    = (const float*)d_in[3];
    const float* b2    = (const float*)d_in[4];
    const float* la1rA = (const float*)d_in[5];
    const float* la1rB = (const float*)d_in[6];
    const float* la1iA = (const float*)d_in[7];
    const float* la1iB = (const float*)d_in[8];
    const float* la2rA = (const float*)d_in[9];
    const float* la2rB = (const float*)d_in[10];
    const float* la2iA = (const float*)d_in[11];
    const float* la2iB = (const float*)d_in[12];
    float* out = (float*)d_out;

    unsigned int* ws = (unsigned int*)d_ws;
    unsigned int* y1 = ws;                 // 8388608 uint (33.5 MB)
    unsigned int* y2 = ws + 8388608;       // 4194304 uint (16.8 MB)
    unsigned int* z2 = ws + 12582912;      // 4194304 uint (16.8 MB)
    unsigned int* zw = ws + 16777216;      // 8388608 uint (33.5 MB)

    hipLaunchKernelGGL(k1a_dft_l,  dim3(2048), dim3(256), 0, stream, x, y1);
    hipLaunchKernelGGL(k1b_dft_w,  dim3(2048), dim3(256), 0, stream, y1, y2);
    hipLaunchKernelGGL(kc_h_mlp,   dim3(1024), dim3(256), 0, stream, y2, z2,
                       w1, b1, w2, b2, la1rA, la1rB, la1iA, la1iB,
                       la2rA, la2rB, la2iA, la2iB);
    hipLaunchKernelGGL(k3a_idft_w, dim3(1024), dim3(256), 0, stream, z2, zw);
    hipLaunchKernelGGL(k3b_idft_l, dim3(2048), dim3(256), 0, stream, x, zw, out);
}